// Round 1
// baseline (2274.463 us; speedup 1.0000x reference)
//
#include <hip/hip_runtime.h>

#define NVIEW 5
#define BATCH 4
#define NPTS 128000
#define CIMG 3
#define CFEAT 32
#define CTOT 35
#define DIN 73
#define HID 256
#define IMG_W 960
#define IMG_H 512
#define HM_W 240
#define HM_H 128

#define BP 32          // points per block
#define HSTR 260       // LDS stride for h (float4-aligned, bank-friendly)

struct Tap {
    int o00, o01, o10, o11;     // (x0,y0) (x1,y0) (x0,y1) (x1,y1) offsets
    float w00, w01, w10, w11;   // weights with validity folded in
};

__device__ inline void make_tap(float gx, float gy, int W, int H, Tap& t) {
    float x = (gx + 1.0f) * 0.5f * (float)(W - 1);
    float y = (gy + 1.0f) * 0.5f * (float)(H - 1);
    float x0 = floorf(x), y0 = floorf(y);
    float x1 = x0 + 1.0f, y1 = y0 + 1.0f;
    float wx1 = x - x0, wy1 = y - y0;
    float wx0 = 1.0f - wx1, wy0 = 1.0f - wy1;
    float vx0 = (x0 >= 0.0f && x0 <= (float)(W - 1)) ? 1.0f : 0.0f;
    float vx1 = (x1 >= 0.0f && x1 <= (float)(W - 1)) ? 1.0f : 0.0f;
    float vy0 = (y0 >= 0.0f && y0 <= (float)(H - 1)) ? 1.0f : 0.0f;
    float vy1 = (y1 >= 0.0f && y1 <= (float)(H - 1)) ? 1.0f : 0.0f;
    int ix0 = min(max((int)x0, 0), W - 1);
    int ix1 = min(max((int)x1, 0), W - 1);
    int iy0 = min(max((int)y0, 0), H - 1);
    int iy1 = min(max((int)y1, 0), H - 1);
    t.o00 = iy0 * W + ix0;  t.w00 = wx0 * wy0 * vx0 * vy0;
    t.o01 = iy0 * W + ix1;  t.w01 = wx1 * wy0 * vx1 * vy0;
    t.o10 = iy1 * W + ix0;  t.w10 = wx0 * wy1 * vx0 * vy1;
    t.o11 = iy1 * W + ix1;  t.w11 = wx1 * wy1 * vx1 * vy1;
}

__global__ __launch_bounds__(256, 3) void fused_denorm_project(
    const float* __restrict__ imgs,   // [V,B,3,512,960]
    const float* __restrict__ feats,  // [V,B,32,128,240]
    const float* __restrict__ grids,  // [B,N,3]
    const float* __restrict__ Rm,     // [V,B,3,3]
    const float* __restrict__ Tm,     // [V,B,3,1]
    const float* __restrict__ fcam,   // [V,B,2]
    const float* __restrict__ ccam,   // [V,B,2]
    const float* __restrict__ kdist,  // [V,B,3]
    const float* __restrict__ pdist,  // [V,B,2]
    const float* __restrict__ trans,  // [2,3]
    const float* __restrict__ W1,     // [73,256]
    const float* __restrict__ b1,     // [256]
    const float* __restrict__ W2,     // [256,256]
    const float* __restrict__ b2,     // [256]
    const float* __restrict__ W3,     // [256,1]
    const float* __restrict__ b3,     // [1]
    float* __restrict__ out)          // [B*N]
{
    __shared__ float featL[BP * DIN];   // 9.3 KB
    __shared__ float hL[BP * HSTR];     // 33.3 KB

    const int tid = threadIdx.x;
    const int blk = blockIdx.x;
    const int b   = blk / (NPTS / BP);
    const int n0  = (blk % (NPTS / BP)) * BP;

    // ================= Phase A: projection + bilinear sampling =================
    {
        const int p = tid & 31;          // point within block
        const int g = tid >> 5;          // channel group 0..7 (channels c = g + 8k)
        const int n = n0 + p;

        const float px = grids[(b * NPTS + n) * 3 + 0];
        const float py = grids[(b * NPTS + n) * 3 + 1];
        const float pz = grids[(b * NPTS + n) * 3 + 2];
        if (g == 0) {
            featL[p * DIN + 0] = px * 1e-3f;
            featL[p * DIN + 1] = py * 1e-3f;
            featL[p * DIN + 2] = pz * 1e-3f;
        }
        const float t00 = trans[0], t01 = trans[1], t02 = trans[2];
        const float t10 = trans[3], t11 = trans[4], t12 = trans[5];

        float s[5] = {0.f, 0.f, 0.f, 0.f, 0.f};
        float q[5] = {0.f, 0.f, 0.f, 0.f, 0.f};

        for (int v = 0; v < NVIEW; ++v) {
            const int vb = v * BATCH + b;
            const float* Rp = Rm + vb * 9;
            const float* Tp = Tm + vb * 3;
            float X = px - Tp[0], Y = py - Tp[1], Z = pz - Tp[2];
            float xc = Rp[0] * X + Rp[1] * Y + Rp[2] * Z;
            float yc = Rp[3] * X + Rp[4] * Y + Rp[5] * Z;
            float zc = Rp[6] * X + Rp[7] * Y + Rp[8] * Z;
            float inv = 1.0f / (zc + 1e-5f);
            float y0 = xc * inv, y1 = yc * inv;
            float r2 = y0 * y0 + y1 * y1;
            float k0 = kdist[vb * 3 + 0], k1 = kdist[vb * 3 + 1], k2 = kdist[vb * 3 + 2];
            float p0 = pdist[vb * 2 + 0], p1 = pdist[vb * 2 + 1];
            float radial = 1.0f + r2 * (k0 + r2 * (k1 + r2 * k2));
            float tn = p0 * y1 + p1 * y0;
            float scl = radial + 2.0f * tn;
            float uu = y0 * scl + p1 * r2;
            float vv = y1 * scl + p0 * r2;
            float xo = fcam[vb * 2 + 0] * uu + ccam[vb * 2 + 0];
            float yo = fcam[vb * 2 + 1] * vv + ccam[vb * 2 + 1];
            xo = fminf(fmaxf(xo, -1.0f), 1920.0f);
            yo = fminf(fmaxf(yo, -1.0f), 1920.0f);
            float xr = t00 * xo + t01 * yo + t02;
            float yr = t10 * xo + t11 * yo + t12;
            float gx = xr * (1.0f / (float)(IMG_W - 1)) * 2.0f - 1.0f;
            float gy = yr * (1.0f / (float)(IMG_H - 1)) * 2.0f - 1.0f;

            Tap tI, tF;
            make_tap(gx, gy, IMG_W, IMG_H, tI);
            make_tap(gx, gy, HM_W, HM_H, tF);
            const float* ibase = imgs  + (size_t)vb * CIMG  * IMG_H * IMG_W;
            const float* fbase = feats + (size_t)vb * CFEAT * HM_H * HM_W;

#pragma unroll
            for (int k = 0; k < 5; ++k) {
                int c = g + 8 * k;
                if (c < CTOT) {
                    float val;
                    if (c < CIMG) {
                        const float* pc = ibase + c * (IMG_H * IMG_W);
                        val = pc[tI.o00] * tI.w00 + pc[tI.o01] * tI.w01 +
                              pc[tI.o10] * tI.w10 + pc[tI.o11] * tI.w11;
                    } else {
                        const float* pc = fbase + (c - CIMG) * (HM_H * HM_W);
                        val = pc[tF.o00] * tF.w00 + pc[tF.o01] * tF.w01 +
                              pc[tF.o10] * tF.w10 + pc[tF.o11] * tF.w11;
                    }
                    s[k] += val;
                    q[k] += val * val;
                }
            }
        }
#pragma unroll
        for (int k = 0; k < 5; ++k) {
            int c = g + 8 * k;
            if (c < CTOT) {
                float mean = s[k] * (1.0f / NVIEW);
                float var  = q[k] * (1.0f / NVIEW) - mean * mean;
                featL[p * DIN + 3 + c]  = mean;
                featL[p * DIN + 38 + c] = expf(-var);
            }
        }
    }
    __syncthreads();

    // ================= MLP =================
    // thread tile: 8 points (own wave's rows) x 4 hidden outputs
    const int jg = tid & 63;         // lane
    const int pg = tid >> 6;         // wave id 0..3; points pg*8..pg*8+7

    float acc[8][4];
#pragma unroll
    for (int pp = 0; pp < 8; ++pp)
#pragma unroll
        for (int jj = 0; jj < 4; ++jj) acc[pp][jj] = 0.0f;

    // ---- layer 1: feat[73] @ W1 -> h1[256] ----
    for (int i = 0; i < DIN; ++i) {
        float wv[4];
#pragma unroll
        for (int jj = 0; jj < 4; ++jj) wv[jj] = W1[i * HID + jg + 64 * jj];
#pragma unroll
        for (int pp = 0; pp < 8; ++pp) {
            float fv = featL[(pg * 8 + pp) * DIN + i];
#pragma unroll
            for (int jj = 0; jj < 4; ++jj) acc[pp][jj] += fv * wv[jj];
        }
    }
    {
        float b1v[4];
#pragma unroll
        for (int jj = 0; jj < 4; ++jj) b1v[jj] = b1[jg + 64 * jj];
#pragma unroll
        for (int pp = 0; pp < 8; ++pp)
#pragma unroll
            for (int jj = 0; jj < 4; ++jj)
                hL[(pg * 8 + pp) * HSTR + jg + 64 * jj] =
                    fmaxf(acc[pp][jj] + b1v[jj], 0.0f);
    }
    __syncthreads();

    // ---- layer 2: h1[256] @ W2 -> h2[256] ----
#pragma unroll
    for (int pp = 0; pp < 8; ++pp)
#pragma unroll
        for (int jj = 0; jj < 4; ++jj) acc[pp][jj] = 0.0f;

    for (int i0 = 0; i0 < HID; i0 += 4) {
        float4 hv[8];
#pragma unroll
        for (int pp = 0; pp < 8; ++pp)
            hv[pp] = *reinterpret_cast<const float4*>(&hL[(pg * 8 + pp) * HSTR + i0]);
        float wv[4][4];
#pragma unroll
        for (int ii = 0; ii < 4; ++ii)
#pragma unroll
            for (int jj = 0; jj < 4; ++jj)
                wv[ii][jj] = W2[(i0 + ii) * HID + jg + 64 * jj];
#pragma unroll
        for (int pp = 0; pp < 8; ++pp) {
#pragma unroll
            for (int jj = 0; jj < 4; ++jj) {
                acc[pp][jj] += hv[pp].x * wv[0][jj];
                acc[pp][jj] += hv[pp].y * wv[1][jj];
                acc[pp][jj] += hv[pp].z * wv[2][jj];
                acc[pp][jj] += hv[pp].w * wv[3][jj];
            }
        }
    }

    // ---- layer 3 (+bias/relu of layer2) fully in registers ----
    float part[8];
    {
        float b2v[4], w3v[4];
#pragma unroll
        for (int jj = 0; jj < 4; ++jj) {
            b2v[jj] = b2[jg + 64 * jj];
            w3v[jj] = W3[jg + 64 * jj];
        }
#pragma unroll
        for (int pp = 0; pp < 8; ++pp) {
            float acc3 = 0.0f;
#pragma unroll
            for (int jj = 0; jj < 4; ++jj)
                acc3 += fmaxf(acc[pp][jj] + b2v[jj], 0.0f) * w3v[jj];
            part[pp] = acc3;
        }
    }
    // wave-wide butterfly reduction over the 256 hidden dims (64 lanes x 4 jj)
#pragma unroll
    for (int off = 32; off >= 1; off >>= 1) {
#pragma unroll
        for (int pp = 0; pp < 8; ++pp)
            part[pp] += __shfl_xor(part[pp], off, 64);
    }

    if ((tid & 63) == 0) {
        const float bb3 = b3[0];
        const int base = b * NPTS + n0 + pg * 8;
        // alpha = 1 - exp(-softplus(x)) == sigmoid(x), exactly
#pragma unroll
        for (int k = 0; k < 8; ++k) {
            float logit = part[k] + bb3;
            out[base + k] = 1.0f / (1.0f + expf(-logit));
        }
    }
}

extern "C" void kernel_launch(void* const* d_in, const int* in_sizes, int n_in,
                              void* d_out, int out_size, void* d_ws, size_t ws_size,
                              hipStream_t stream) {
    const float* imgs  = (const float*)d_in[0];
    const float* feats = (const float*)d_in[1];
    const float* grids = (const float*)d_in[2];
    const float* Rm    = (const float*)d_in[3];
    const float* Tm    = (const float*)d_in[4];
    const float* fcam  = (const float*)d_in[5];
    const float* ccam  = (const float*)d_in[6];
    const float* kdist = (const float*)d_in[7];
    const float* pdist = (const float*)d_in[8];
    const float* trans = (const float*)d_in[9];
    const float* W1    = (const float*)d_in[10];
    const float* b1    = (const float*)d_in[11];
    const float* W2    = (const float*)d_in[12];
    const float* b2    = (const float*)d_in[13];
    const float* W3    = (const float*)d_in[14];
    const float* b3    = (const float*)d_in[15];
    float* out = (float*)d_out;

    const int nblocks = BATCH * (NPTS / BP);  // 16000
    fused_denorm_project<<<nblocks, 256, 0, stream>>>(
        imgs, feats, grids, Rm, Tm, fcam, ccam, kdist, pdist, trans,
        W1, b1, W2, b2, W3, b3, out);
}

// Round 2
// 1565.805 us; speedup vs baseline: 1.4526x; 1.4526x over previous
//
#include <hip/hip_runtime.h>

#define NVIEW 5
#define BATCH 4
#define NPTS 128000
#define CIMG 3
#define CFEAT 32
#define CTOT 35
#define DIN 73
#define HID 256
#define IMG_W 960
#define IMG_H 512
#define HM_W 240
#define HM_H 128
#define HW_IMG (IMG_W * IMG_H)   // 491520
#define HW_HM (HM_W * HM_H)      // 30720

#define BP 32          // points per block
#define HSTR 260       // LDS stride for h (float4-aligned, bank-friendly)

struct Tap {
    int o00, o01, o10, o11;     // pixel offsets (y*W+x)
    float w00, w01, w10, w11;   // weights with validity folded in
};

__device__ inline void make_tap(float gx, float gy, int W, int H, Tap& t) {
    float x = (gx + 1.0f) * 0.5f * (float)(W - 1);
    float y = (gy + 1.0f) * 0.5f * (float)(H - 1);
    float x0 = floorf(x), y0 = floorf(y);
    float x1 = x0 + 1.0f, y1 = y0 + 1.0f;
    float wx1 = x - x0, wy1 = y - y0;
    float wx0 = 1.0f - wx1, wy0 = 1.0f - wy1;
    float vx0 = (x0 >= 0.0f && x0 <= (float)(W - 1)) ? 1.0f : 0.0f;
    float vx1 = (x1 >= 0.0f && x1 <= (float)(W - 1)) ? 1.0f : 0.0f;
    float vy0 = (y0 >= 0.0f && y0 <= (float)(H - 1)) ? 1.0f : 0.0f;
    float vy1 = (y1 >= 0.0f && y1 <= (float)(H - 1)) ? 1.0f : 0.0f;
    int ix0 = min(max((int)x0, 0), W - 1);
    int ix1 = min(max((int)x1, 0), W - 1);
    int iy0 = min(max((int)y0, 0), H - 1);
    int iy1 = min(max((int)y1, 0), H - 1);
    t.o00 = iy0 * W + ix0;  t.w00 = wx0 * wy0 * vx0 * vy0;
    t.o01 = iy0 * W + ix1;  t.w01 = wx1 * wy0 * vx1 * vy0;
    t.o10 = iy1 * W + ix0;  t.w10 = wx0 * wy1 * vx0 * vy1;
    t.o11 = iy1 * W + ix1;  t.w11 = wx1 * wy1 * vx1 * vy1;
}

__device__ inline float4 f4zero() { float4 r; r.x = r.y = r.z = r.w = 0.f; return r; }
__device__ inline float4 f4fma(float w, float4 a, float4 acc) {
    acc.x += w * a.x; acc.y += w * a.y; acc.z += w * a.z; acc.w += w * a.w; return acc;
}
__device__ inline float4 f4add(float4 a, float4 b) {
    a.x += b.x; a.y += b.y; a.z += b.z; a.w += b.w; return a;
}
__device__ inline float4 f4addsq(float4 acc, float4 v) {
    acc.x += v.x * v.x; acc.y += v.y * v.y; acc.z += v.z * v.z; acc.w += v.w * v.w; return acc;
}

// ---------------- layout transpose pre-passes ----------------
// imgs [V*B, 3, H, W] -> ws0 [V*B, H, W, 4] (c=3 zero pad)
__global__ __launch_bounds__(256) void transpose_img(const float* __restrict__ in,
                                                     float* __restrict__ out) {
    int idx = blockIdx.x * 256 + threadIdx.x;          // < 20*HW_IMG
    int vb = idx / HW_IMG;
    int pix = idx - vb * HW_IMG;
    const float* src = in + (size_t)vb * 3 * HW_IMG + pix;
    float4 o;
    o.x = src[0];
    o.y = src[HW_IMG];
    o.z = src[2 * HW_IMG];
    o.w = 0.0f;
    reinterpret_cast<float4*>(out)[idx] = o;
}

// feats [V*B, 32, h, w] -> ws1 [V*B, h, w, 32]
__global__ __launch_bounds__(256) void transpose_feat(const float* __restrict__ in,
                                                      float* __restrict__ out) {
    int idx = blockIdx.x * 256 + threadIdx.x;          // < 20*HW_HM
    int vb = idx / HW_HM;
    int pix = idx - vb * HW_HM;
    const float* src = in + (size_t)vb * 32 * HW_HM + pix;
    float4* dst = reinterpret_cast<float4*>(out) + (size_t)idx * 8;
#pragma unroll
    for (int k = 0; k < 8; ++k) {
        float4 o;
        o.x = src[(4 * k + 0) * HW_HM];
        o.y = src[(4 * k + 1) * HW_HM];
        o.z = src[(4 * k + 2) * HW_HM];
        o.w = src[(4 * k + 3) * HW_HM];
        dst[k] = o;
    }
}

// ---------------- main fused kernel ----------------
__global__ __launch_bounds__(256, 3) void fused_denorm_project(
    const float* __restrict__ wsImg,  // [V*B, H, W, 4]
    const float* __restrict__ wsFeat, // [V*B, h, w, 32]
    const float* __restrict__ grids,  // [B,N,3]
    const float* __restrict__ Rm,     // [V,B,3,3]
    const float* __restrict__ Tm,     // [V,B,3,1]
    const float* __restrict__ fcam,   // [V,B,2]
    const float* __restrict__ ccam,   // [V,B,2]
    const float* __restrict__ kdist,  // [V,B,3]
    const float* __restrict__ pdist,  // [V,B,2]
    const float* __restrict__ trans,  // [2,3]
    const float* __restrict__ W1,     // [73,256]
    const float* __restrict__ b1,     // [256]
    const float* __restrict__ W2,     // [256,256]
    const float* __restrict__ b2,     // [256]
    const float* __restrict__ W3,     // [256,1]
    const float* __restrict__ b3,     // [1]
    float* __restrict__ out)          // [B*N]
{
    __shared__ float featL[BP * DIN];   // 9.3 KB
    __shared__ float hL[BP * HSTR];     // 33.3 KB

    const int tid = threadIdx.x;
    const int blk = blockIdx.x;
    const int b   = blk / (NPTS / BP);
    const int n0  = (blk % (NPTS / BP)) * BP;

    // ====== Phase A: projection + channel-interleaved bilinear sampling ======
    {
        const int t = tid & 7;           // chunk id: feat channels 4t..4t+3
        const int p = tid >> 3;          // point within block (0..31)
        const int n = n0 + p;

        const float px = grids[(b * NPTS + n) * 3 + 0];
        const float py = grids[(b * NPTS + n) * 3 + 1];
        const float pz = grids[(b * NPTS + n) * 3 + 2];
        if (t == 1) {
            featL[p * DIN + 0] = px * 1e-3f;
            featL[p * DIN + 1] = py * 1e-3f;
            featL[p * DIN + 2] = pz * 1e-3f;
        }
        const float t00 = trans[0], t01 = trans[1], t02 = trans[2];
        const float t10 = trans[3], t11 = trans[4], t12 = trans[5];

        float4 s4 = f4zero(), q4 = f4zero();     // feat chunk sums
        float4 si = f4zero(), qi = f4zero();     // img sums (t==0 only)

        for (int v = 0; v < NVIEW; ++v) {
            const int vb = v * BATCH + b;
            const float* Rp = Rm + vb * 9;
            const float* Tp = Tm + vb * 3;
            float X = px - Tp[0], Y = py - Tp[1], Z = pz - Tp[2];
            float xc = Rp[0] * X + Rp[1] * Y + Rp[2] * Z;
            float yc = Rp[3] * X + Rp[4] * Y + Rp[5] * Z;
            float zc = Rp[6] * X + Rp[7] * Y + Rp[8] * Z;
            float inv = 1.0f / (zc + 1e-5f);
            float y0 = xc * inv, y1 = yc * inv;
            float r2 = y0 * y0 + y1 * y1;
            float k0 = kdist[vb * 3 + 0], k1 = kdist[vb * 3 + 1], k2 = kdist[vb * 3 + 2];
            float p0 = pdist[vb * 2 + 0], p1 = pdist[vb * 2 + 1];
            float radial = 1.0f + r2 * (k0 + r2 * (k1 + r2 * k2));
            float tn = p0 * y1 + p1 * y0;
            float scl = radial + 2.0f * tn;
            float uu = y0 * scl + p1 * r2;
            float vv = y1 * scl + p0 * r2;
            float xo = fcam[vb * 2 + 0] * uu + ccam[vb * 2 + 0];
            float yo = fcam[vb * 2 + 1] * vv + ccam[vb * 2 + 1];
            xo = fminf(fmaxf(xo, -1.0f), 1920.0f);
            yo = fminf(fmaxf(yo, -1.0f), 1920.0f);
            float xr = t00 * xo + t01 * yo + t02;
            float yr = t10 * xo + t11 * yo + t12;
            float gx = xr * (1.0f / (float)(IMG_W - 1)) * 2.0f - 1.0f;
            float gy = yr * (1.0f / (float)(IMG_H - 1)) * 2.0f - 1.0f;

            // ---- feature heatmap chunk (all 8 threads) ----
            Tap tF;
            make_tap(gx, gy, HM_W, HM_H, tF);
            const float4* fb = reinterpret_cast<const float4*>(
                wsFeat + (size_t)vb * HW_HM * 32) + t;
            float4 a00 = fb[tF.o00 * 8];
            float4 a01 = fb[tF.o01 * 8];
            float4 a10 = fb[tF.o10 * 8];
            float4 a11 = fb[tF.o11 * 8];
            float4 val = f4zero();
            val = f4fma(tF.w00, a00, val);
            val = f4fma(tF.w01, a01, val);
            val = f4fma(tF.w10, a10, val);
            val = f4fma(tF.w11, a11, val);
            s4 = f4add(s4, val);
            q4 = f4addsq(q4, val);

            // ---- image chunk (thread 0 of each point) ----
            if (t == 0) {
                Tap tI;
                make_tap(gx, gy, IMG_W, IMG_H, tI);
                const float4* ib = reinterpret_cast<const float4*>(
                    wsImg + (size_t)vb * HW_IMG * 4);
                float4 i00 = ib[tI.o00];
                float4 i01 = ib[tI.o01];
                float4 i10 = ib[tI.o10];
                float4 i11 = ib[tI.o11];
                float4 vi = f4zero();
                vi = f4fma(tI.w00, i00, vi);
                vi = f4fma(tI.w01, i01, vi);
                vi = f4fma(tI.w10, i10, vi);
                vi = f4fma(tI.w11, i11, vi);
                si = f4add(si, vi);
                qi = f4addsq(qi, vi);
            }
        }

        // mean / exp(-var) write-out
        const float inv5 = 1.0f / (float)NVIEW;
        {
            float m0 = s4.x * inv5, m1 = s4.y * inv5, m2 = s4.z * inv5, m3 = s4.w * inv5;
            float* fm = &featL[p * DIN + 6 + 4 * t];   // mean of feat chans (3 img first)
            float* fv = &featL[p * DIN + 41 + 4 * t];
            fm[0] = m0; fm[1] = m1; fm[2] = m2; fm[3] = m3;
            fv[0] = expf(-(q4.x * inv5 - m0 * m0));
            fv[1] = expf(-(q4.y * inv5 - m1 * m1));
            fv[2] = expf(-(q4.z * inv5 - m2 * m2));
            fv[3] = expf(-(q4.w * inv5 - m3 * m3));
        }
        if (t == 0) {
            float m0 = si.x * inv5, m1 = si.y * inv5, m2 = si.z * inv5;
            featL[p * DIN + 3] = m0;
            featL[p * DIN + 4] = m1;
            featL[p * DIN + 5] = m2;
            featL[p * DIN + 38] = expf(-(qi.x * inv5 - m0 * m0));
            featL[p * DIN + 39] = expf(-(qi.y * inv5 - m1 * m1));
            featL[p * DIN + 40] = expf(-(qi.z * inv5 - m2 * m2));
        }
    }
    __syncthreads();

    // ================= MLP =================
    const int jg = tid & 63;         // lane
    const int pg = tid >> 6;         // wave id 0..3; points pg*8..pg*8+7

    float acc[8][4];
#pragma unroll
    for (int pp = 0; pp < 8; ++pp)
#pragma unroll
        for (int jj = 0; jj < 4; ++jj) acc[pp][jj] = 0.0f;

    // ---- layer 1: feat[73] @ W1 -> h1[256] ----
    for (int i = 0; i < DIN; ++i) {
        float wv[4];
#pragma unroll
        for (int jj = 0; jj < 4; ++jj) wv[jj] = W1[i * HID + jg + 64 * jj];
#pragma unroll
        for (int pp = 0; pp < 8; ++pp) {
            float fv = featL[(pg * 8 + pp) * DIN + i];
#pragma unroll
            for (int jj = 0; jj < 4; ++jj) acc[pp][jj] += fv * wv[jj];
        }
    }
    {
        float b1v[4];
#pragma unroll
        for (int jj = 0; jj < 4; ++jj) b1v[jj] = b1[jg + 64 * jj];
#pragma unroll
        for (int pp = 0; pp < 8; ++pp)
#pragma unroll
            for (int jj = 0; jj < 4; ++jj)
                hL[(pg * 8 + pp) * HSTR + jg + 64 * jj] =
                    fmaxf(acc[pp][jj] + b1v[jj], 0.0f);
    }
    __syncthreads();

    // ---- layer 2: h1[256] @ W2 -> h2[256] ----
#pragma unroll
    for (int pp = 0; pp < 8; ++pp)
#pragma unroll
        for (int jj = 0; jj < 4; ++jj) acc[pp][jj] = 0.0f;

    for (int i0 = 0; i0 < HID; i0 += 4) {
        float4 hv[8];
#pragma unroll
        for (int pp = 0; pp < 8; ++pp)
            hv[pp] = *reinterpret_cast<const float4*>(&hL[(pg * 8 + pp) * HSTR + i0]);
        float wv[4][4];
#pragma unroll
        for (int ii = 0; ii < 4; ++ii)
#pragma unroll
            for (int jj = 0; jj < 4; ++jj)
                wv[ii][jj] = W2[(i0 + ii) * HID + jg + 64 * jj];
#pragma unroll
        for (int pp = 0; pp < 8; ++pp) {
#pragma unroll
            for (int jj = 0; jj < 4; ++jj) {
                acc[pp][jj] += hv[pp].x * wv[0][jj];
                acc[pp][jj] += hv[pp].y * wv[1][jj];
                acc[pp][jj] += hv[pp].z * wv[2][jj];
                acc[pp][jj] += hv[pp].w * wv[3][jj];
            }
        }
    }

    // ---- layer 3 (+bias/relu of layer2) fully in registers ----
    float part[8];
    {
        float b2v[4], w3v[4];
#pragma unroll
        for (int jj = 0; jj < 4; ++jj) {
            b2v[jj] = b2[jg + 64 * jj];
            w3v[jj] = W3[jg + 64 * jj];
        }
#pragma unroll
        for (int pp = 0; pp < 8; ++pp) {
            float acc3 = 0.0f;
#pragma unroll
            for (int jj = 0; jj < 4; ++jj)
                acc3 += fmaxf(acc[pp][jj] + b2v[jj], 0.0f) * w3v[jj];
            part[pp] = acc3;
        }
    }
#pragma unroll
    for (int off = 32; off >= 1; off >>= 1) {
#pragma unroll
        for (int pp = 0; pp < 8; ++pp)
            part[pp] += __shfl_xor(part[pp], off, 64);
    }

    if ((tid & 63) == 0) {
        const float bb3 = b3[0];
        const int base = b * NPTS + n0 + pg * 8;
        // alpha = 1 - exp(-softplus(x)) == sigmoid(x), exactly
#pragma unroll
        for (int k = 0; k < 8; ++k) {
            float logit = part[k] + bb3;
            out[base + k] = 1.0f / (1.0f + expf(-logit));
        }
    }
}

extern "C" void kernel_launch(void* const* d_in, const int* in_sizes, int n_in,
                              void* d_out, int out_size, void* d_ws, size_t ws_size,
                              hipStream_t stream) {
    const float* imgs  = (const float*)d_in[0];
    const float* feats = (const float*)d_in[1];
    const float* grids = (const float*)d_in[2];
    const float* Rm    = (const float*)d_in[3];
    const float* Tm    = (const float*)d_in[4];
    const float* fcam  = (const float*)d_in[5];
    const float* ccam  = (const float*)d_in[6];
    const float* kdist = (const float*)d_in[7];
    const float* pdist = (const float*)d_in[8];
    const float* trans = (const float*)d_in[9];
    const float* W1    = (const float*)d_in[10];
    const float* b1    = (const float*)d_in[11];
    const float* W2    = (const float*)d_in[12];
    const float* b2    = (const float*)d_in[13];
    const float* W3    = (const float*)d_in[14];
    const float* b3    = (const float*)d_in[15];
    float* out = (float*)d_out;

    float* wsImg  = (float*)d_ws;                          // 20*HW_IMG*4 floats (157 MB)
    float* wsFeat = wsImg + (size_t)NVIEW * BATCH * HW_IMG * 4;  // 20*HW_HM*32 floats (79 MB)

    // layout transposes (per-call; d_ws is re-poisoned before every launch)
    transpose_img<<<(NVIEW * BATCH * HW_IMG) / 256, 256, 0, stream>>>(imgs, wsImg);
    transpose_feat<<<(NVIEW * BATCH * HW_HM) / 256, 256, 0, stream>>>(feats, wsFeat);

    const int nblocks = BATCH * (NPTS / BP);  // 16000
    fused_denorm_project<<<nblocks, 256, 0, stream>>>(
        wsImg, wsFeat, grids, Rm, Tm, fcam, ccam, kdist, pdist, trans,
        W1, b1, W2, b2, W3, b3, out);
}

// Round 3
// 564.730 us; speedup vs baseline: 4.0275x; 2.7727x over previous
//
#include <hip/hip_runtime.h>

#define NVIEW 5
#define BATCH 4
#define NPTS 128000
#define CIMG 3
#define CFEAT 32
#define CTOT 35
#define DIN 73
#define HID 256
#define IMG_W 960
#define IMG_H 512
#define HM_W 240
#define HM_H 128
#define HW_IMG (IMG_W * IMG_H)   // 491520
#define HW_HM (HM_W * HM_H)      // 30720

#define BP 32          // points per block

typedef __attribute__((ext_vector_type(8))) short bf16x8;
typedef __attribute__((ext_vector_type(4))) float f32x4;
typedef __attribute__((ext_vector_type(4))) unsigned short ushort4v;
typedef __attribute__((ext_vector_type(8))) unsigned short ushort8v;

__device__ inline unsigned short bf16_rtne(float f) {
    unsigned u = __builtin_bit_cast(unsigned, f);
    u += 0x7FFFu + ((u >> 16) & 1u);
    return (unsigned short)(u >> 16);
}

struct Tap {
    int o00, o01, o10, o11;     // pixel offsets (y*W+x)
    float w00, w01, w10, w11;   // weights with validity folded in
};

__device__ inline void make_tap(float gx, float gy, int W, int H, Tap& t) {
    float x = (gx + 1.0f) * 0.5f * (float)(W - 1);
    float y = (gy + 1.0f) * 0.5f * (float)(H - 1);
    float x0 = floorf(x), y0 = floorf(y);
    float x1 = x0 + 1.0f, y1 = y0 + 1.0f;
    float wx1 = x - x0, wy1 = y - y0;
    float wx0 = 1.0f - wx1, wy0 = 1.0f - wy1;
    float vx0 = (x0 >= 0.0f && x0 <= (float)(W - 1)) ? 1.0f : 0.0f;
    float vx1 = (x1 >= 0.0f && x1 <= (float)(W - 1)) ? 1.0f : 0.0f;
    float vy0 = (y0 >= 0.0f && y0 <= (float)(H - 1)) ? 1.0f : 0.0f;
    float vy1 = (y1 >= 0.0f && y1 <= (float)(H - 1)) ? 1.0f : 0.0f;
    int ix0 = min(max((int)x0, 0), W - 1);
    int ix1 = min(max((int)x1, 0), W - 1);
    int iy0 = min(max((int)y0, 0), H - 1);
    int iy1 = min(max((int)y1, 0), H - 1);
    t.o00 = iy0 * W + ix0;  t.w00 = wx0 * wy0 * vx0 * vy0;
    t.o01 = iy0 * W + ix1;  t.w01 = wx1 * wy0 * vx1 * vy0;
    t.o10 = iy1 * W + ix0;  t.w10 = wx0 * wy1 * vx0 * vy1;
    t.o11 = iy1 * W + ix1;  t.w11 = wx1 * wy1 * vx1 * vy1;
}

__device__ inline float4 f4zero() { float4 r; r.x = r.y = r.z = r.w = 0.f; return r; }
__device__ inline float4 f4fma(float w, float4 a, float4 acc) {
    acc.x += w * a.x; acc.y += w * a.y; acc.z += w * a.z; acc.w += w * a.w; return acc;
}
__device__ inline float4 f4add(float4 a, float4 b) {
    a.x += b.x; a.y += b.y; a.z += b.z; a.w += b.w; return a;
}
__device__ inline float4 f4addsq(float4 acc, float4 v) {
    acc.x += v.x * v.x; acc.y += v.y * v.y; acc.z += v.z * v.z; acc.w += v.w * v.w; return acc;
}

// ---------------- layout transpose pre-passes ----------------
__global__ __launch_bounds__(256) void transpose_img(const float* __restrict__ in,
                                                     float* __restrict__ out) {
    int idx = blockIdx.x * 256 + threadIdx.x;          // < 20*HW_IMG
    int vb = idx / HW_IMG;
    int pix = idx - vb * HW_IMG;
    const float* src = in + (size_t)vb * 3 * HW_IMG + pix;
    float4 o;
    o.x = src[0];
    o.y = src[HW_IMG];
    o.z = src[2 * HW_IMG];
    o.w = 0.0f;
    reinterpret_cast<float4*>(out)[idx] = o;
}

__global__ __launch_bounds__(256) void transpose_feat(const float* __restrict__ in,
                                                      float* __restrict__ out) {
    int idx = blockIdx.x * 256 + threadIdx.x;          // < 20*HW_HM
    int vb = idx / HW_HM;
    int pix = idx - vb * HW_HM;
    const float* src = in + (size_t)vb * 32 * HW_HM + pix;
    float4* dst = reinterpret_cast<float4*>(out) + (size_t)idx * 8;
#pragma unroll
    for (int k = 0; k < 8; ++k) {
        float4 o;
        o.x = src[(4 * k + 0) * HW_HM];
        o.y = src[(4 * k + 1) * HW_HM];
        o.z = src[(4 * k + 2) * HW_HM];
        o.w = src[(4 * k + 3) * HW_HM];
        dst[k] = o;
    }
}

// ---------------- weight fragment pre-pack (f32 -> bf16, MFMA A-frag order) ----
// W1b[nt][ks][lane][8]: nt<16, ks<3;  value = W1[ks*32+(l>>4)*8+j][nt*16+(l&15)], 0 if k>=73
// W2b[nt][ks][lane][8]: nt<16, ks<8;  value = W2[ks*32+(l>>4)*8+j][nt*16+(l&15)]
__global__ __launch_bounds__(256) void prep_weights(const float* __restrict__ W1,
                                                    const float* __restrict__ W2,
                                                    unsigned short* __restrict__ W1b,
                                                    unsigned short* __restrict__ W2b) {
    int idx = blockIdx.x * 256 + threadIdx.x;   // 44 blocks -> 11264 threads
    if (idx < 16 * 3 * 64) {
        int l = idx & 63;
        int ks = (idx >> 6) % 3;
        // nt = idx / 192 (implicit in linear index)
        int nt = idx / 192;
        int n = nt * 16 + (l & 15);
        int k0 = ks * 32 + (l >> 4) * 8;
        ushort8v o;
#pragma unroll
        for (int j = 0; j < 8; ++j) {
            int k = k0 + j;
            float v = (k < DIN) ? W1[k * HID + n] : 0.0f;
            o[j] = bf16_rtne(v);
        }
        reinterpret_cast<ushort8v*>(W1b)[idx] = o;
    } else if (idx < 16 * 3 * 64 + 16 * 8 * 64) {
        int id2 = idx - 16 * 3 * 64;
        int l = id2 & 63;
        int ks = (id2 >> 6) & 7;
        int nt = id2 >> 9;
        int n = nt * 16 + (l & 15);
        int k0 = ks * 32 + (l >> 4) * 8;
        ushort8v o;
#pragma unroll
        for (int j = 0; j < 8; ++j)
            o[j] = bf16_rtne(W2[(k0 + j) * HID + n]);
        reinterpret_cast<ushort8v*>(W2b)[id2] = o;
    }
}

// ---------------- main fused kernel ----------------
__global__ __launch_bounds__(256, 4) void fused_denorm_project(
    const float* __restrict__ wsImg,  // [V*B, H, W, 4]
    const float* __restrict__ wsFeat, // [V*B, h, w, 32]
    const unsigned short* __restrict__ W1b,
    const unsigned short* __restrict__ W2b,
    const float* __restrict__ grids,  // [B,N,3]
    const float* __restrict__ Rm,     // [V,B,3,3]
    const float* __restrict__ Tm,     // [V,B,3,1]
    const float* __restrict__ fcam,   // [V,B,2]
    const float* __restrict__ ccam,   // [V,B,2]
    const float* __restrict__ kdist,  // [V,B,3]
    const float* __restrict__ pdist,  // [V,B,2]
    const float* __restrict__ trans,  // [2,3]
    const float* __restrict__ b1,     // [256]
    const float* __restrict__ b2,     // [256]
    const float* __restrict__ W3,     // [256,1]
    const float* __restrict__ b3,     // [1]
    float* __restrict__ out)          // [B*N]
{
    // featb: bf16 [32 p][96 k], row stride 192 B, XOR-swizzled ((p&7)<<4)
    __shared__ unsigned short featb[BP * 96];    // 6 KB
    // h1T: bf16 [32 p][256 n], row stride 512 B, same swizzle
    __shared__ unsigned short h1T[BP * 256];     // 16 KB
    __shared__ float b1L[HID], b2L[HID], w3L[HID];
    __shared__ float partial[4][BP];

    const int tid = threadIdx.x;
    const int blk = blockIdx.x;
    const int b   = blk / (NPTS / BP);
    const int n0  = (blk % (NPTS / BP)) * BP;

    // biases / W3 -> LDS (issue early, covered by the phase-A barrier)
    b1L[tid] = b1[tid];
    b2L[tid] = b2[tid];
    w3L[tid] = W3[tid];

    // ====== Phase A: projection + channel-interleaved bilinear sampling ======
    {
        const int t = tid & 7;           // chunk id: feat channels 4t..4t+3
        const int p = tid >> 3;          // point within block (0..31)
        const int n = n0 + p;
        char* fbB = (char*)featb;
        const int rowoff = p * 192;
        const int sw = (p & 7) << 4;

        const float px = grids[(b * NPTS + n) * 3 + 0];
        const float py = grids[(b * NPTS + n) * 3 + 1];
        const float pz = grids[(b * NPTS + n) * 3 + 2];
        if (t == 1) {
            *(unsigned short*)(fbB + ((rowoff + 0) ^ sw)) = bf16_rtne(px * 1e-3f);
            *(unsigned short*)(fbB + ((rowoff + 2) ^ sw)) = bf16_rtne(py * 1e-3f);
            *(unsigned short*)(fbB + ((rowoff + 4) ^ sw)) = bf16_rtne(pz * 1e-3f);
        }
        // zero-pad k = 73..95
        {
            int c0 = 73 + t * 3;
            int cnt = (t == 7) ? 2 : 3;
            for (int j = 0; j < cnt; ++j)
                *(unsigned short*)(fbB + ((rowoff + (c0 + j) * 2) ^ sw)) = 0;
        }
        const float t00 = trans[0], t01 = trans[1], t02 = trans[2];
        const float t10 = trans[3], t11 = trans[4], t12 = trans[5];

        float4 s4 = f4zero(), q4 = f4zero();     // feat chunk sums
        float4 si = f4zero(), qi = f4zero();     // img sums (t==0 only)

        for (int v = 0; v < NVIEW; ++v) {
            const int vb = v * BATCH + b;
            const float* Rp = Rm + vb * 9;
            const float* Tp = Tm + vb * 3;
            float X = px - Tp[0], Y = py - Tp[1], Z = pz - Tp[2];
            float xc = Rp[0] * X + Rp[1] * Y + Rp[2] * Z;
            float yc = Rp[3] * X + Rp[4] * Y + Rp[5] * Z;
            float zc = Rp[6] * X + Rp[7] * Y + Rp[8] * Z;
            float inv = 1.0f / (zc + 1e-5f);
            float y0 = xc * inv, y1 = yc * inv;
            float r2 = y0 * y0 + y1 * y1;
            float k0 = kdist[vb * 3 + 0], k1 = kdist[vb * 3 + 1], k2 = kdist[vb * 3 + 2];
            float p0 = pdist[vb * 2 + 0], p1 = pdist[vb * 2 + 1];
            float radial = 1.0f + r2 * (k0 + r2 * (k1 + r2 * k2));
            float tn = p0 * y1 + p1 * y0;
            float scl = radial + 2.0f * tn;
            float uu = y0 * scl + p1 * r2;
            float vv = y1 * scl + p0 * r2;
            float xo = fcam[vb * 2 + 0] * uu + ccam[vb * 2 + 0];
            float yo = fcam[vb * 2 + 1] * vv + ccam[vb * 2 + 1];
            xo = fminf(fmaxf(xo, -1.0f), 1920.0f);
            yo = fminf(fmaxf(yo, -1.0f), 1920.0f);
            float xr = t00 * xo + t01 * yo + t02;
            float yr = t10 * xo + t11 * yo + t12;
            float gx = xr * (1.0f / (float)(IMG_W - 1)) * 2.0f - 1.0f;
            float gy = yr * (1.0f / (float)(IMG_H - 1)) * 2.0f - 1.0f;

            Tap tF;
            make_tap(gx, gy, HM_W, HM_H, tF);
            const float4* fb = reinterpret_cast<const float4*>(
                wsFeat + (size_t)vb * HW_HM * 32) + t;
            float4 a00 = fb[tF.o00 * 8];
            float4 a01 = fb[tF.o01 * 8];
            float4 a10 = fb[tF.o10 * 8];
            float4 a11 = fb[tF.o11 * 8];
            float4 val = f4zero();
            val = f4fma(tF.w00, a00, val);
            val = f4fma(tF.w01, a01, val);
            val = f4fma(tF.w10, a10, val);
            val = f4fma(tF.w11, a11, val);
            s4 = f4add(s4, val);
            q4 = f4addsq(q4, val);

            if (t == 0) {
                Tap tI;
                make_tap(gx, gy, IMG_W, IMG_H, tI);
                const float4* ib = reinterpret_cast<const float4*>(
                    wsImg + (size_t)vb * HW_IMG * 4);
                float4 i00 = ib[tI.o00];
                float4 i01 = ib[tI.o01];
                float4 i10 = ib[tI.o10];
                float4 i11 = ib[tI.o11];
                float4 vi = f4zero();
                vi = f4fma(tI.w00, i00, vi);
                vi = f4fma(tI.w01, i01, vi);
                vi = f4fma(tI.w10, i10, vi);
                vi = f4fma(tI.w11, i11, vi);
                si = f4add(si, vi);
                qi = f4addsq(qi, vi);
            }
        }

        const float inv5 = 1.0f / (float)NVIEW;
        {
            float m0 = s4.x * inv5, m1 = s4.y * inv5, m2 = s4.z * inv5, m3 = s4.w * inv5;
            int cm = 6 + 4 * t;     // mean channels
            int cv = 41 + 4 * t;    // var channels
            *(unsigned short*)(fbB + ((rowoff + (cm + 0) * 2) ^ sw)) = bf16_rtne(m0);
            *(unsigned short*)(fbB + ((rowoff + (cm + 1) * 2) ^ sw)) = bf16_rtne(m1);
            *(unsigned short*)(fbB + ((rowoff + (cm + 2) * 2) ^ sw)) = bf16_rtne(m2);
            *(unsigned short*)(fbB + ((rowoff + (cm + 3) * 2) ^ sw)) = bf16_rtne(m3);
            *(unsigned short*)(fbB + ((rowoff + (cv + 0) * 2) ^ sw)) = bf16_rtne(expf(-(q4.x * inv5 - m0 * m0)));
            *(unsigned short*)(fbB + ((rowoff + (cv + 1) * 2) ^ sw)) = bf16_rtne(expf(-(q4.y * inv5 - m1 * m1)));
            *(unsigned short*)(fbB + ((rowoff + (cv + 2) * 2) ^ sw)) = bf16_rtne(expf(-(q4.z * inv5 - m2 * m2)));
            *(unsigned short*)(fbB + ((rowoff + (cv + 3) * 2) ^ sw)) = bf16_rtne(expf(-(q4.w * inv5 - m3 * m3)));
        }
        if (t == 0) {
            float m0 = si.x * inv5, m1 = si.y * inv5, m2 = si.z * inv5;
            *(unsigned short*)(fbB + ((rowoff + 3 * 2) ^ sw)) = bf16_rtne(m0);
            *(unsigned short*)(fbB + ((rowoff + 4 * 2) ^ sw)) = bf16_rtne(m1);
            *(unsigned short*)(fbB + ((rowoff + 5 * 2) ^ sw)) = bf16_rtne(m2);
            *(unsigned short*)(fbB + ((rowoff + 38 * 2) ^ sw)) = bf16_rtne(expf(-(qi.x * inv5 - m0 * m0)));
            *(unsigned short*)(fbB + ((rowoff + 39 * 2) ^ sw)) = bf16_rtne(expf(-(qi.y * inv5 - m1 * m1)));
            *(unsigned short*)(fbB + ((rowoff + 40 * 2) ^ sw)) = bf16_rtne(expf(-(qi.z * inv5 - m2 * m2)));
        }
    }
    __syncthreads();

    // ================= MLP via MFMA (transposed: h^T[n][p]) =================
    const int l   = tid & 63;
    const int w   = tid >> 6;          // wave 0..3, owns n-tiles w*4..w*4+3
    const int g   = l >> 4;            // lane group
    const int c16 = l & 15;            // point-within-tile (B col), also D col

    // ---- layer 1: h1T[n][p] = relu(W1^T @ feat^T + b1), K=96 (padded) ----
    {
        f32x4 acc[4][2];
#pragma unroll
        for (int nl = 0; nl < 4; ++nl)
#pragma unroll
            for (int pt = 0; pt < 2; ++pt) acc[nl][pt] = (f32x4)0.0f;

        const bf16x8* wfrag = reinterpret_cast<const bf16x8*>(W1b);
#pragma unroll
        for (int ks = 0; ks < 3; ++ks) {
            bf16x8 bfr[2];
#pragma unroll
            for (int pt = 0; pt < 2; ++pt) {
                int p = pt * 16 + c16;
                int off = (p * 192 + (ks * 32 + g * 8) * 2) ^ ((p & 7) << 4);
                bfr[pt] = *reinterpret_cast<const bf16x8*>((const char*)featb + off);
            }
#pragma unroll
            for (int nl = 0; nl < 4; ++nl) {
                int nt = w * 4 + nl;
                bf16x8 a = wfrag[(nt * 3 + ks) * 64 + l];
                acc[nl][0] = __builtin_amdgcn_mfma_f32_16x16x32_bf16(a, bfr[0], acc[nl][0], 0, 0, 0);
                acc[nl][1] = __builtin_amdgcn_mfma_f32_16x16x32_bf16(a, bfr[1], acc[nl][1], 0, 0, 0);
            }
        }
        // epilogue: bias + relu -> bf16 -> h1T (swizzled)
#pragma unroll
        for (int nl = 0; nl < 4; ++nl) {
            int nb = (w * 4 + nl) * 16 + g * 4;     // first of 4 consecutive n rows
            float bb0 = b1L[nb + 0], bb1 = b1L[nb + 1], bb2 = b1L[nb + 2], bb3v = b1L[nb + 3];
#pragma unroll
            for (int pt = 0; pt < 2; ++pt) {
                int p = pt * 16 + c16;
                ushort4v pk;
                pk[0] = bf16_rtne(fmaxf(acc[nl][pt][0] + bb0, 0.0f));
                pk[1] = bf16_rtne(fmaxf(acc[nl][pt][1] + bb1, 0.0f));
                pk[2] = bf16_rtne(fmaxf(acc[nl][pt][2] + bb2, 0.0f));
                pk[3] = bf16_rtne(fmaxf(acc[nl][pt][3] + bb3v, 0.0f));
                int off = (p * 512 + nb * 2) ^ ((p & 7) << 4);
                *reinterpret_cast<ushort4v*>((char*)h1T + off) = pk;
            }
        }
    }
    __syncthreads();

    // ---- layer 2 + layer 3: h2T[n][p] -> per-lane dot with W3 ----
    {
        f32x4 acc[4][2];
#pragma unroll
        for (int nl = 0; nl < 4; ++nl)
#pragma unroll
            for (int pt = 0; pt < 2; ++pt) acc[nl][pt] = (f32x4)0.0f;

        const bf16x8* wfrag = reinterpret_cast<const bf16x8*>(W2b);
#pragma unroll
        for (int ks = 0; ks < 8; ++ks) {
            bf16x8 bfr[2];
#pragma unroll
            for (int pt = 0; pt < 2; ++pt) {
                int p = pt * 16 + c16;
                int off = (p * 512 + (ks * 32 + g * 8) * 2) ^ ((p & 7) << 4);
                bfr[pt] = *reinterpret_cast<const bf16x8*>((const char*)h1T + off);
            }
#pragma unroll
            for (int nl = 0; nl < 4; ++nl) {
                int nt = w * 4 + nl;
                bf16x8 a = wfrag[(nt * 8 + ks) * 64 + l];
                acc[nl][0] = __builtin_amdgcn_mfma_f32_16x16x32_bf16(a, bfr[0], acc[nl][0], 0, 0, 0);
                acc[nl][1] = __builtin_amdgcn_mfma_f32_16x16x32_bf16(a, bfr[1], acc[nl][1], 0, 0, 0);
            }
        }
        // epilogue: bias+relu, dot with W3 (per-lane: 16 n-values of its point)
        float s0 = 0.0f, s1 = 0.0f;
#pragma unroll
        for (int nl = 0; nl < 4; ++nl) {
            int nb = (w * 4 + nl) * 16 + g * 4;
#pragma unroll
            for (int r = 0; r < 4; ++r) {
                float b2v = b2L[nb + r];
                float w3v = w3L[nb + r];
                s0 += fmaxf(acc[nl][0][r] + b2v, 0.0f) * w3v;
                s1 += fmaxf(acc[nl][1][r] + b2v, 0.0f) * w3v;
            }
        }
        // reduce over lane groups g (same point across g)
        s0 += __shfl_xor(s0, 16, 64);
        s0 += __shfl_xor(s0, 32, 64);
        s1 += __shfl_xor(s1, 16, 64);
        s1 += __shfl_xor(s1, 32, 64);
        if (g == 0) {
            partial[w][c16]      = s0;
            partial[w][16 + c16] = s1;
        }
    }
    __syncthreads();

    if (tid < BP) {
        float v = partial[0][tid] + partial[1][tid] + partial[2][tid] + partial[3][tid] + b3[0];
        out[b * NPTS + n0 + tid] = 1.0f / (1.0f + expf(-v));   // 1-exp(-softplus) == sigmoid
    }
}

extern "C" void kernel_launch(void* const* d_in, const int* in_sizes, int n_in,
                              void* d_out, int out_size, void* d_ws, size_t ws_size,
                              hipStream_t stream) {
    const float* imgs  = (const float*)d_in[0];
    const float* feats = (const float*)d_in[1];
    const float* grids = (const float*)d_in[2];
    const float* Rm    = (const float*)d_in[3];
    const float* Tm    = (const float*)d_in[4];
    const float* fcam  = (const float*)d_in[5];
    const float* ccam  = (const float*)d_in[6];
    const float* kdist = (const float*)d_in[7];
    const float* pdist = (const float*)d_in[8];
    const float* trans = (const float*)d_in[9];
    const float* W1    = (const float*)d_in[10];
    const float* b1    = (const float*)d_in[11];
    const float* W2    = (const float*)d_in[12];
    const float* b2    = (const float*)d_in[13];
    const float* W3    = (const float*)d_in[14];
    const float* b3    = (const float*)d_in[15];
    float* out = (float*)d_out;

    float* wsImg  = (float*)d_ws;                                   // 157 MB
    float* wsFeat = wsImg + (size_t)NVIEW * BATCH * HW_IMG * 4;     // 79 MB
    unsigned short* W1b = (unsigned short*)(wsFeat + (size_t)NVIEW * BATCH * HW_HM * 32);
    unsigned short* W2b = W1b + 16 * 3 * 64 * 8;                    // 48 KB after W1b
    // W2b: 16*8*64*8 ushort = 128 KB

    transpose_img<<<(NVIEW * BATCH * HW_IMG) / 256, 256, 0, stream>>>(imgs, wsImg);
    transpose_feat<<<(NVIEW * BATCH * HW_HM) / 256, 256, 0, stream>>>(feats, wsFeat);
    prep_weights<<<44, 256, 0, stream>>>(W1, W2, W1b, W2b);

    const int nblocks = BATCH * (NPTS / BP);  // 16000
    fused_denorm_project<<<nblocks, 256, 0, stream>>>(
        wsImg, wsFeat, W1b, W2b, grids, Rm, Tm, fcam, ccam, kdist, pdist, trans,
        b1, b2, W3, b3, out);
}

// Round 4
// 509.035 us; speedup vs baseline: 4.4682x; 1.1094x over previous
//
#include <hip/hip_runtime.h>

#define NVIEW 5
#define BATCH 4
#define NPTS 128000
#define CIMG 3
#define CFEAT 32
#define CTOT 35
#define DIN 73
#define HID 256
#define IMG_W 960
#define IMG_H 512
#define HM_W 240
#define HM_H 128
#define HW_IMG (IMG_W * IMG_H)   // 491520
#define HW_HM (HM_W * HM_H)      // 30720

#define BP 32          // points per block

typedef __attribute__((ext_vector_type(8))) short bf16x8;
typedef __attribute__((ext_vector_type(4))) float f32x4;
typedef __attribute__((ext_vector_type(4))) unsigned short ushort4v;
typedef __attribute__((ext_vector_type(8))) unsigned short ushort8v;

__device__ inline unsigned short bf16_rtne(float f) {
    unsigned u = __builtin_bit_cast(unsigned, f);
    u += 0x7FFFu + ((u >> 16) & 1u);
    return (unsigned short)(u >> 16);
}
__device__ inline float bf2f(unsigned short u) {
    return __builtin_bit_cast(float, ((unsigned)u) << 16);
}

struct Tap {
    int o00, o01, o10, o11;     // pixel offsets (y*W+x)
    float w00, w01, w10, w11;   // weights with validity folded in
};

__device__ inline void make_tap(float gx, float gy, int W, int H, Tap& t) {
    float x = (gx + 1.0f) * 0.5f * (float)(W - 1);
    float y = (gy + 1.0f) * 0.5f * (float)(H - 1);
    float x0 = floorf(x), y0 = floorf(y);
    float x1 = x0 + 1.0f, y1 = y0 + 1.0f;
    float wx1 = x - x0, wy1 = y - y0;
    float wx0 = 1.0f - wx1, wy0 = 1.0f - wy1;
    float vx0 = (x0 >= 0.0f && x0 <= (float)(W - 1)) ? 1.0f : 0.0f;
    float vx1 = (x1 >= 0.0f && x1 <= (float)(W - 1)) ? 1.0f : 0.0f;
    float vy0 = (y0 >= 0.0f && y0 <= (float)(H - 1)) ? 1.0f : 0.0f;
    float vy1 = (y1 >= 0.0f && y1 <= (float)(H - 1)) ? 1.0f : 0.0f;
    int ix0 = min(max((int)x0, 0), W - 1);
    int ix1 = min(max((int)x1, 0), W - 1);
    int iy0 = min(max((int)y0, 0), H - 1);
    int iy1 = min(max((int)y1, 0), H - 1);
    t.o00 = iy0 * W + ix0;  t.w00 = wx0 * wy0 * vx0 * vy0;
    t.o01 = iy0 * W + ix1;  t.w01 = wx1 * wy0 * vx1 * vy0;
    t.o10 = iy1 * W + ix0;  t.w10 = wx0 * wy1 * vx0 * vy1;
    t.o11 = iy1 * W + ix1;  t.w11 = wx1 * wy1 * vx1 * vy1;
}

__device__ inline float4 f4zero() { float4 r; r.x = r.y = r.z = r.w = 0.f; return r; }
__device__ inline float4 tapacc(ushort4v a, float w, float4 acc) {
    acc.x += w * bf2f(a[0]); acc.y += w * bf2f(a[1]);
    acc.z += w * bf2f(a[2]); acc.w += w * bf2f(a[3]); return acc;
}
__device__ inline float4 f4add(float4 a, float4 b) {
    a.x += b.x; a.y += b.y; a.z += b.z; a.w += b.w; return a;
}
__device__ inline float4 f4addsq(float4 acc, float4 v) {
    acc.x += v.x * v.x; acc.y += v.y * v.y; acc.z += v.z * v.z; acc.w += v.w * v.w; return acc;
}

// ---------------- layout transpose pre-passes (f32 -> bf16 interleaved) -----
// imgs [V*B, 3, H, W] f32 -> wsImg [V*B, H, W, 4] bf16 (ch3 = 0); 4 px/thread
__global__ __launch_bounds__(256) void transpose_img(const float* __restrict__ in,
                                                     unsigned short* __restrict__ out) {
    int idx = blockIdx.x * 256 + threadIdx.x;            // < 20*HW_IMG/4
    int vb = idx / (HW_IMG / 4);
    int p4 = idx - vb * (HW_IMG / 4);
    const float* src = in + (size_t)vb * 3 * HW_IMG + p4 * 4;
    float4 c0 = *reinterpret_cast<const float4*>(src);
    float4 c1 = *reinterpret_cast<const float4*>(src + HW_IMG);
    float4 c2 = *reinterpret_cast<const float4*>(src + 2 * HW_IMG);
    ushort8v o01, o23;
    o01[0] = bf16_rtne(c0.x); o01[1] = bf16_rtne(c1.x); o01[2] = bf16_rtne(c2.x); o01[3] = 0;
    o01[4] = bf16_rtne(c0.y); o01[5] = bf16_rtne(c1.y); o01[6] = bf16_rtne(c2.y); o01[7] = 0;
    o23[0] = bf16_rtne(c0.z); o23[1] = bf16_rtne(c1.z); o23[2] = bf16_rtne(c2.z); o23[3] = 0;
    o23[4] = bf16_rtne(c0.w); o23[5] = bf16_rtne(c1.w); o23[6] = bf16_rtne(c2.w); o23[7] = 0;
    ushort8v* dst = reinterpret_cast<ushort8v*>(out + ((size_t)vb * HW_IMG + p4 * 4) * 4);
    dst[0] = o01;
    dst[1] = o23;
}

// feats [V*B, 32, h, w] f32 -> wsFeat [V*B, h, w, 32] bf16; 1 px/thread
__global__ __launch_bounds__(256) void transpose_feat(const float* __restrict__ in,
                                                      unsigned short* __restrict__ out) {
    int idx = blockIdx.x * 256 + threadIdx.x;            // < 20*HW_HM
    int vb = idx / HW_HM;
    int pix = idx - vb * HW_HM;
    const float* src = in + (size_t)vb * 32 * HW_HM + pix;
    ushort8v* dst = reinterpret_cast<ushort8v*>(out + (size_t)idx * 32);
#pragma unroll
    for (int k = 0; k < 4; ++k) {
        ushort8v o;
#pragma unroll
        for (int j = 0; j < 8; ++j)
            o[j] = bf16_rtne(src[(8 * k + j) * HW_HM]);
        dst[k] = o;
    }
}

// ---------------- weight fragment pre-pack (f32 -> bf16, MFMA A-frag order) ----
__global__ __launch_bounds__(256) void prep_weights(const float* __restrict__ W1,
                                                    const float* __restrict__ W2,
                                                    unsigned short* __restrict__ W1b,
                                                    unsigned short* __restrict__ W2b) {
    int idx = blockIdx.x * 256 + threadIdx.x;   // 44 blocks -> 11264 threads
    if (idx < 16 * 3 * 64) {
        int l = idx & 63;
        int ks = (idx >> 6) % 3;
        int nt = idx / 192;
        int n = nt * 16 + (l & 15);
        int k0 = ks * 32 + (l >> 4) * 8;
        ushort8v o;
#pragma unroll
        for (int j = 0; j < 8; ++j) {
            int k = k0 + j;
            float v = (k < DIN) ? W1[k * HID + n] : 0.0f;
            o[j] = bf16_rtne(v);
        }
        reinterpret_cast<ushort8v*>(W1b)[idx] = o;
    } else if (idx < 16 * 3 * 64 + 16 * 8 * 64) {
        int id2 = idx - 16 * 3 * 64;
        int l = id2 & 63;
        int ks = (id2 >> 6) & 7;
        int nt = id2 >> 9;
        int n = nt * 16 + (l & 15);
        int k0 = ks * 32 + (l >> 4) * 8;
        ushort8v o;
#pragma unroll
        for (int j = 0; j < 8; ++j)
            o[j] = bf16_rtne(W2[(k0 + j) * HID + n]);
        reinterpret_cast<ushort8v*>(W2b)[id2] = o;
    }
}

// ---------------- main fused kernel ----------------
__global__ __launch_bounds__(256, 4) void fused_denorm_project(
    const unsigned short* __restrict__ wsImg,  // [V*B, H, W, 4] bf16
    const unsigned short* __restrict__ wsFeat, // [V*B, h, w, 32] bf16
    const unsigned short* __restrict__ W1b,
    const unsigned short* __restrict__ W2b,
    const float* __restrict__ grids,  // [B,N,3]
    const float* __restrict__ Rm,     // [V,B,3,3]
    const float* __restrict__ Tm,     // [V,B,3,1]
    const float* __restrict__ fcam,   // [V,B,2]
    const float* __restrict__ ccam,   // [V,B,2]
    const float* __restrict__ kdist,  // [V,B,3]
    const float* __restrict__ pdist,  // [V,B,2]
    const float* __restrict__ trans,  // [2,3]
    const float* __restrict__ b1,     // [256]
    const float* __restrict__ b2,     // [256]
    const float* __restrict__ W3,     // [256,1]
    const float* __restrict__ b3,     // [1]
    float* __restrict__ out)          // [B*N]
{
    __shared__ unsigned short featb[BP * 96];    // 6 KB, swizzle ((p&7)<<4)
    __shared__ unsigned short h1T[BP * 256];     // 16 KB, same swizzle
    __shared__ float b1L[HID], b2L[HID], w3L[HID];
    __shared__ float partial[4][BP];

    const int tid = threadIdx.x;
    const int blk = blockIdx.x;
    const int b   = blk / (NPTS / BP);
    const int n0  = (blk % (NPTS / BP)) * BP;

    b1L[tid] = b1[tid];
    b2L[tid] = b2[tid];
    w3L[tid] = W3[tid];

    // ====== Phase A: one-view-per-lane projection + shared sampling ======
    {
        const int t = tid & 7;           // 8-lane group slot; feat chans 4t..4t+3
        const int p = tid >> 3;          // point within block (0..31)
        const int n = n0 + p;
        char* fbB = (char*)featb;
        const int rowoff = p * 192;
        const int sw = (p & 7) << 4;

        const float px = grids[(b * NPTS + n) * 3 + 0];
        const float py = grids[(b * NPTS + n) * 3 + 1];
        const float pz = grids[(b * NPTS + n) * 3 + 2];
        if (t == 1) {
            *(unsigned short*)(fbB + ((rowoff + 0) ^ sw)) = bf16_rtne(px * 1e-3f);
            *(unsigned short*)(fbB + ((rowoff + 2) ^ sw)) = bf16_rtne(py * 1e-3f);
            *(unsigned short*)(fbB + ((rowoff + 4) ^ sw)) = bf16_rtne(pz * 1e-3f);
        }
        {   // zero-pad k = 73..95
            int c0 = 73 + t * 3;
            int cnt = (t == 7) ? 2 : 3;
            for (int j = 0; j < cnt; ++j)
                *(unsigned short*)(fbB + ((rowoff + (c0 + j) * 2) ^ sw)) = 0;
        }

        // ---- owner lane (t < 5) computes view t's projection + taps ----
        Tap myF = {}; Tap myI = {};
        if (t < NVIEW) {
            const int vb = t * BATCH + b;
            const float* Rp = Rm + vb * 9;
            const float* Tp = Tm + vb * 3;
            float X = px - Tp[0], Y = py - Tp[1], Z = pz - Tp[2];
            float xc = Rp[0] * X + Rp[1] * Y + Rp[2] * Z;
            float yc = Rp[3] * X + Rp[4] * Y + Rp[5] * Z;
            float zc = Rp[6] * X + Rp[7] * Y + Rp[8] * Z;
            float inv = 1.0f / (zc + 1e-5f);
            float y0 = xc * inv, y1 = yc * inv;
            float r2 = y0 * y0 + y1 * y1;
            float k0 = kdist[vb * 3 + 0], k1 = kdist[vb * 3 + 1], k2 = kdist[vb * 3 + 2];
            float p0 = pdist[vb * 2 + 0], p1 = pdist[vb * 2 + 1];
            float radial = 1.0f + r2 * (k0 + r2 * (k1 + r2 * k2));
            float tn = p0 * y1 + p1 * y0;
            float scl = radial + 2.0f * tn;
            float uu = y0 * scl + p1 * r2;
            float vv = y1 * scl + p0 * r2;
            float xo = fcam[vb * 2 + 0] * uu + ccam[vb * 2 + 0];
            float yo = fcam[vb * 2 + 1] * vv + ccam[vb * 2 + 1];
            xo = fminf(fmaxf(xo, -1.0f), 1920.0f);
            yo = fminf(fmaxf(yo, -1.0f), 1920.0f);
            float xr = trans[0] * xo + trans[1] * yo + trans[2];
            float yr = trans[3] * xo + trans[4] * yo + trans[5];
            float gx = xr * (1.0f / (float)(IMG_W - 1)) * 2.0f - 1.0f;
            float gy = yr * (1.0f / (float)(IMG_H - 1)) * 2.0f - 1.0f;
            make_tap(gx, gy, HM_W, HM_H, myF);
            make_tap(gx, gy, IMG_W, IMG_H, myI);
        }

        // ---- feat sampling: all 8 lanes, taps broadcast from owner lane ----
        float4 s4 = f4zero(), q4 = f4zero();
        const int lb = (tid & 63) & 56;     // wave-local group base
        for (int v = 0; v < NVIEW; ++v) {
            const int src = lb + v;
            Tap tF;
            tF.o00 = __shfl(myF.o00, src, 64);
            tF.o01 = __shfl(myF.o01, src, 64);
            tF.o10 = __shfl(myF.o10, src, 64);
            tF.o11 = __shfl(myF.o11, src, 64);
            tF.w00 = __shfl(myF.w00, src, 64);
            tF.w01 = __shfl(myF.w01, src, 64);
            tF.w10 = __shfl(myF.w10, src, 64);
            tF.w11 = __shfl(myF.w11, src, 64);
            const unsigned short* fb = wsFeat + (size_t)(v * BATCH + b) * HW_HM * 32 + t * 4;
            ushort4v a00 = *reinterpret_cast<const ushort4v*>(fb + (size_t)tF.o00 * 32);
            ushort4v a01 = *reinterpret_cast<const ushort4v*>(fb + (size_t)tF.o01 * 32);
            ushort4v a10 = *reinterpret_cast<const ushort4v*>(fb + (size_t)tF.o10 * 32);
            ushort4v a11 = *reinterpret_cast<const ushort4v*>(fb + (size_t)tF.o11 * 32);
            float4 val = f4zero();
            val = tapacc(a00, tF.w00, val);
            val = tapacc(a01, tF.w01, val);
            val = tapacc(a10, tF.w10, val);
            val = tapacc(a11, tF.w11, val);
            s4 = f4add(s4, val);
            q4 = f4addsq(q4, val);
        }

        // ---- img sampling: owner lane samples its own view ----
        float4 si = f4zero(), qi = f4zero();
        if (t < NVIEW) {
            const unsigned short* ib = wsImg + (size_t)(t * BATCH + b) * HW_IMG * 4;
            ushort4v i00 = *reinterpret_cast<const ushort4v*>(ib + (size_t)myI.o00 * 4);
            ushort4v i01 = *reinterpret_cast<const ushort4v*>(ib + (size_t)myI.o01 * 4);
            ushort4v i10 = *reinterpret_cast<const ushort4v*>(ib + (size_t)myI.o10 * 4);
            ushort4v i11 = *reinterpret_cast<const ushort4v*>(ib + (size_t)myI.o11 * 4);
            float4 vi = f4zero();
            vi = tapacc(i00, myI.w00, vi);
            vi = tapacc(i01, myI.w01, vi);
            vi = tapacc(i10, myI.w10, vi);
            vi = tapacc(i11, myI.w11, vi);
            si = vi;
            qi = f4addsq(f4zero(), vi);
        }
        // 8-lane butterfly reduce of si/qi (lanes 5..7 contribute zero)
#pragma unroll
        for (int off = 1; off <= 4; off <<= 1) {
            si.x += __shfl_xor(si.x, off, 64);
            si.y += __shfl_xor(si.y, off, 64);
            si.z += __shfl_xor(si.z, off, 64);
            qi.x += __shfl_xor(qi.x, off, 64);
            qi.y += __shfl_xor(qi.y, off, 64);
            qi.z += __shfl_xor(qi.z, off, 64);
        }

        const float inv5 = 1.0f / (float)NVIEW;
        {
            float m0 = s4.x * inv5, m1 = s4.y * inv5, m2 = s4.z * inv5, m3 = s4.w * inv5;
            int cm = 6 + 4 * t;
            int cv = 41 + 4 * t;
            *(unsigned short*)(fbB + ((rowoff + (cm + 0) * 2) ^ sw)) = bf16_rtne(m0);
            *(unsigned short*)(fbB + ((rowoff + (cm + 1) * 2) ^ sw)) = bf16_rtne(m1);
            *(unsigned short*)(fbB + ((rowoff + (cm + 2) * 2) ^ sw)) = bf16_rtne(m2);
            *(unsigned short*)(fbB + ((rowoff + (cm + 3) * 2) ^ sw)) = bf16_rtne(m3);
            *(unsigned short*)(fbB + ((rowoff + (cv + 0) * 2) ^ sw)) = bf16_rtne(expf(-(q4.x * inv5 - m0 * m0)));
            *(unsigned short*)(fbB + ((rowoff + (cv + 1) * 2) ^ sw)) = bf16_rtne(expf(-(q4.y * inv5 - m1 * m1)));
            *(unsigned short*)(fbB + ((rowoff + (cv + 2) * 2) ^ sw)) = bf16_rtne(expf(-(q4.z * inv5 - m2 * m2)));
            *(unsigned short*)(fbB + ((rowoff + (cv + 3) * 2) ^ sw)) = bf16_rtne(expf(-(q4.w * inv5 - m3 * m3)));
        }
        if (t == 0) {
            float m0 = si.x * inv5, m1 = si.y * inv5, m2 = si.z * inv5;
            *(unsigned short*)(fbB + ((rowoff + 3 * 2) ^ sw)) = bf16_rtne(m0);
            *(unsigned short*)(fbB + ((rowoff + 4 * 2) ^ sw)) = bf16_rtne(m1);
            *(unsigned short*)(fbB + ((rowoff + 5 * 2) ^ sw)) = bf16_rtne(m2);
            *(unsigned short*)(fbB + ((rowoff + 38 * 2) ^ sw)) = bf16_rtne(expf(-(qi.x * inv5 - m0 * m0)));
            *(unsigned short*)(fbB + ((rowoff + 39 * 2) ^ sw)) = bf16_rtne(expf(-(qi.y * inv5 - m1 * m1)));
            *(unsigned short*)(fbB + ((rowoff + 40 * 2) ^ sw)) = bf16_rtne(expf(-(qi.z * inv5 - m2 * m2)));
        }
    }
    __syncthreads();

    // ================= MLP via MFMA (transposed: h^T[n][p]) =================
    const int l   = tid & 63;
    const int w   = tid >> 6;          // wave 0..3, owns n-tiles w*4..w*4+3
    const int g   = l >> 4;            // lane group
    const int c16 = l & 15;            // point-within-tile

    // ---- layer 1 ----
    {
        f32x4 acc[4][2];
#pragma unroll
        for (int nl = 0; nl < 4; ++nl)
#pragma unroll
            for (int pt = 0; pt < 2; ++pt) acc[nl][pt] = (f32x4)0.0f;

        const bf16x8* wfrag = reinterpret_cast<const bf16x8*>(W1b);
#pragma unroll
        for (int ks = 0; ks < 3; ++ks) {
            bf16x8 bfr[2];
#pragma unroll
            for (int pt = 0; pt < 2; ++pt) {
                int p = pt * 16 + c16;
                int off = (p * 192 + (ks * 32 + g * 8) * 2) ^ ((p & 7) << 4);
                bfr[pt] = *reinterpret_cast<const bf16x8*>((const char*)featb + off);
            }
#pragma unroll
            for (int nl = 0; nl < 4; ++nl) {
                int nt = w * 4 + nl;
                bf16x8 a = wfrag[(nt * 3 + ks) * 64 + l];
                acc[nl][0] = __builtin_amdgcn_mfma_f32_16x16x32_bf16(a, bfr[0], acc[nl][0], 0, 0, 0);
                acc[nl][1] = __builtin_amdgcn_mfma_f32_16x16x32_bf16(a, bfr[1], acc[nl][1], 0, 0, 0);
            }
        }
#pragma unroll
        for (int nl = 0; nl < 4; ++nl) {
            int nb = (w * 4 + nl) * 16 + g * 4;
            float bb0 = b1L[nb + 0], bb1 = b1L[nb + 1], bb2 = b1L[nb + 2], bb3v = b1L[nb + 3];
#pragma unroll
            for (int pt = 0; pt < 2; ++pt) {
                int p = pt * 16 + c16;
                ushort4v pk;
                pk[0] = bf16_rtne(fmaxf(acc[nl][pt][0] + bb0, 0.0f));
                pk[1] = bf16_rtne(fmaxf(acc[nl][pt][1] + bb1, 0.0f));
                pk[2] = bf16_rtne(fmaxf(acc[nl][pt][2] + bb2, 0.0f));
                pk[3] = bf16_rtne(fmaxf(acc[nl][pt][3] + bb3v, 0.0f));
                int off = (p * 512 + nb * 2) ^ ((p & 7) << 4);
                *reinterpret_cast<ushort4v*>((char*)h1T + off) = pk;
            }
        }
    }
    __syncthreads();

    // ---- layer 2 + layer 3 ----
    {
        f32x4 acc[4][2];
#pragma unroll
        for (int nl = 0; nl < 4; ++nl)
#pragma unroll
            for (int pt = 0; pt < 2; ++pt) acc[nl][pt] = (f32x4)0.0f;

        const bf16x8* wfrag = reinterpret_cast<const bf16x8*>(W2b);
#pragma unroll
        for (int ks = 0; ks < 8; ++ks) {
            bf16x8 bfr[2];
#pragma unroll
            for (int pt = 0; pt < 2; ++pt) {
                int p = pt * 16 + c16;
                int off = (p * 512 + (ks * 32 + g * 8) * 2) ^ ((p & 7) << 4);
                bfr[pt] = *reinterpret_cast<const bf16x8*>((const char*)h1T + off);
            }
#pragma unroll
            for (int nl = 0; nl < 4; ++nl) {
                int nt = w * 4 + nl;
                bf16x8 a = wfrag[(nt * 8 + ks) * 64 + l];
                acc[nl][0] = __builtin_amdgcn_mfma_f32_16x16x32_bf16(a, bfr[0], acc[nl][0], 0, 0, 0);
                acc[nl][1] = __builtin_amdgcn_mfma_f32_16x16x32_bf16(a, bfr[1], acc[nl][1], 0, 0, 0);
            }
        }
        float s0 = 0.0f, s1 = 0.0f;
#pragma unroll
        for (int nl = 0; nl < 4; ++nl) {
            int nb = (w * 4 + nl) * 16 + g * 4;
#pragma unroll
            for (int r = 0; r < 4; ++r) {
                float b2v = b2L[nb + r];
                float w3v = w3L[nb + r];
                s0 += fmaxf(acc[nl][0][r] + b2v, 0.0f) * w3v;
                s1 += fmaxf(acc[nl][1][r] + b2v, 0.0f) * w3v;
            }
        }
        s0 += __shfl_xor(s0, 16, 64);
        s0 += __shfl_xor(s0, 32, 64);
        s1 += __shfl_xor(s1, 16, 64);
        s1 += __shfl_xor(s1, 32, 64);
        if (g == 0) {
            partial[w][c16]      = s0;
            partial[w][16 + c16] = s1;
        }
    }
    __syncthreads();

    if (tid < BP) {
        float v = partial[0][tid] + partial[1][tid] + partial[2][tid] + partial[3][tid] + b3[0];
        out[b * NPTS + n0 + tid] = 1.0f / (1.0f + expf(-v));   // 1-exp(-softplus) == sigmoid
    }
}

extern "C" void kernel_launch(void* const* d_in, const int* in_sizes, int n_in,
                              void* d_out, int out_size, void* d_ws, size_t ws_size,
                              hipStream_t stream) {
    const float* imgs  = (const float*)d_in[0];
    const float* feats = (const float*)d_in[1];
    const float* grids = (const float*)d_in[2];
    const float* Rm    = (const float*)d_in[3];
    const float* Tm    = (const float*)d_in[4];
    const float* fcam  = (const float*)d_in[5];
    const float* ccam  = (const float*)d_in[6];
    const float* kdist = (const float*)d_in[7];
    const float* pdist = (const float*)d_in[8];
    const float* trans = (const float*)d_in[9];
    const float* W1    = (const float*)d_in[10];
    const float* b1    = (const float*)d_in[11];
    const float* W2    = (const float*)d_in[12];
    const float* b2    = (const float*)d_in[13];
    const float* W3    = (const float*)d_in[14];
    const float* b3    = (const float*)d_in[15];
    float* out = (float*)d_out;

    unsigned short* wsImg  = (unsigned short*)d_ws;                       // 78.6 MB
    unsigned short* wsFeat = wsImg + (size_t)NVIEW * BATCH * HW_IMG * 4;  // 39.3 MB
    unsigned short* W1b    = wsFeat + (size_t)NVIEW * BATCH * HW_HM * 32;
    unsigned short* W2b    = W1b + 16 * 3 * 64 * 8;

    transpose_img<<<(NVIEW * BATCH * HW_IMG / 4) / 256, 256, 0, stream>>>(imgs, wsImg);
    transpose_feat<<<(NVIEW * BATCH * HW_HM) / 256, 256, 0, stream>>>(feats, wsFeat);
    prep_weights<<<44, 256, 0, stream>>>(W1, W2, W1b, W2b);

    const int nblocks = BATCH * (NPTS / BP);  // 16000
    fused_denorm_project<<<nblocks, 256, 0, stream>>>(
        wsImg, wsFeat, W1b, W2b, grids, Rm, Tm, fcam, ccam, kdist, pdist, trans,
        b1, b2, W3, b3, out);
}

// Round 5
// 490.422 us; speedup vs baseline: 4.6378x; 1.0380x over previous
//
#include <hip/hip_runtime.h>

#define NVIEW 5
#define BATCH 4
#define NPTS 128000
#define CIMG 3
#define CFEAT 32
#define CTOT 35
#define DIN 73
#define HID 256
#define IMG_W 960
#define IMG_H 512
#define HM_W 240
#define HM_H 128
#define HW_IMG (IMG_W * IMG_H)   // 491520
#define HW_HM (HM_W * HM_H)      // 30720

#define BP 32          // points per block

// prep_all block-range split
#define NB_IMG  (NVIEW * BATCH * HW_IMG / 4 / 256)   // 9600
#define NB_FEAT (NVIEW * BATCH * HW_HM / 256)        // 2400
#define NB_W    44

typedef __attribute__((ext_vector_type(8))) short bf16x8;
typedef __attribute__((ext_vector_type(4))) float f32x4;
typedef __attribute__((ext_vector_type(4))) unsigned short ushort4v;
typedef __attribute__((ext_vector_type(8))) unsigned short ushort8v;

__device__ inline unsigned short bf16_rtne(float f) {
    unsigned u = __builtin_bit_cast(unsigned, f);
    u += 0x7FFFu + ((u >> 16) & 1u);
    return (unsigned short)(u >> 16);
}
__device__ inline float bf2f(unsigned short u) {
    return __builtin_bit_cast(float, ((unsigned)u) << 16);
}

struct Tap {
    int o00, o01, o10, o11;     // pixel offsets (y*W+x)
    float w00, w01, w10, w11;   // weights with validity folded in
};

__device__ inline void make_tap(float gx, float gy, int W, int H, Tap& t) {
    float x = (gx + 1.0f) * 0.5f * (float)(W - 1);
    float y = (gy + 1.0f) * 0.5f * (float)(H - 1);
    float x0 = floorf(x), y0 = floorf(y);
    float x1 = x0 + 1.0f, y1 = y0 + 1.0f;
    float wx1 = x - x0, wy1 = y - y0;
    float wx0 = 1.0f - wx1, wy0 = 1.0f - wy1;
    float vx0 = (x0 >= 0.0f && x0 <= (float)(W - 1)) ? 1.0f : 0.0f;
    float vx1 = (x1 >= 0.0f && x1 <= (float)(W - 1)) ? 1.0f : 0.0f;
    float vy0 = (y0 >= 0.0f && y0 <= (float)(H - 1)) ? 1.0f : 0.0f;
    float vy1 = (y1 >= 0.0f && y1 <= (float)(H - 1)) ? 1.0f : 0.0f;
    int ix0 = min(max((int)x0, 0), W - 1);
    int ix1 = min(max((int)x1, 0), W - 1);
    int iy0 = min(max((int)y0, 0), H - 1);
    int iy1 = min(max((int)y1, 0), H - 1);
    t.o00 = iy0 * W + ix0;  t.w00 = wx0 * wy0 * vx0 * vy0;
    t.o01 = iy0 * W + ix1;  t.w01 = wx1 * wy0 * vx1 * vy0;
    t.o10 = iy1 * W + ix0;  t.w10 = wx0 * wy1 * vx0 * vy1;
    t.o11 = iy1 * W + ix1;  t.w11 = wx1 * wy1 * vx1 * vy1;
}

__device__ inline float4 f4zero() { float4 r; r.x = r.y = r.z = r.w = 0.f; return r; }
__device__ inline float4 tapacc(ushort4v a, float w, float4 acc) {
    acc.x += w * bf2f(a[0]); acc.y += w * bf2f(a[1]);
    acc.z += w * bf2f(a[2]); acc.w += w * bf2f(a[3]); return acc;
}
__device__ inline float4 f4add(float4 a, float4 b) {
    a.x += b.x; a.y += b.y; a.z += b.z; a.w += b.w; return a;
}
__device__ inline float4 f4addsq(float4 acc, float4 v) {
    acc.x += v.x * v.x; acc.y += v.y * v.y; acc.z += v.z * v.z; acc.w += v.w * v.w; return acc;
}

// =============== single merged prep kernel ===============
// blocks [0, NB_IMG)              : img transpose f32[VB,3,H,W] -> bf16[VB,H,W,4]
// blocks [NB_IMG, NB_IMG+NB_FEAT) : feat transpose f32[VB,32,h,w] -> bf16[VB,h,w,32]
// blocks [.., +NB_W)              : weight pack -> MFMA A-frag order
__global__ __launch_bounds__(256) void prep_all(const float* __restrict__ imgs,
                                                const float* __restrict__ feats,
                                                const float* __restrict__ W1,
                                                const float* __restrict__ W2,
                                                unsigned short* __restrict__ wsImg,
                                                unsigned short* __restrict__ wsFeat,
                                                unsigned short* __restrict__ W1b,
                                                unsigned short* __restrict__ W2b) {
    int blk = blockIdx.x;
    if (blk < NB_IMG) {
        int idx = blk * 256 + threadIdx.x;               // < 20*HW_IMG/4
        int vb = idx / (HW_IMG / 4);
        int p4 = idx - vb * (HW_IMG / 4);
        const float* src = imgs + (size_t)vb * 3 * HW_IMG + p4 * 4;
        float4 c0 = *reinterpret_cast<const float4*>(src);
        float4 c1 = *reinterpret_cast<const float4*>(src + HW_IMG);
        float4 c2 = *reinterpret_cast<const float4*>(src + 2 * HW_IMG);
        ushort8v o01, o23;
        o01[0] = bf16_rtne(c0.x); o01[1] = bf16_rtne(c1.x); o01[2] = bf16_rtne(c2.x); o01[3] = 0;
        o01[4] = bf16_rtne(c0.y); o01[5] = bf16_rtne(c1.y); o01[6] = bf16_rtne(c2.y); o01[7] = 0;
        o23[0] = bf16_rtne(c0.z); o23[1] = bf16_rtne(c1.z); o23[2] = bf16_rtne(c2.z); o23[3] = 0;
        o23[4] = bf16_rtne(c0.w); o23[5] = bf16_rtne(c1.w); o23[6] = bf16_rtne(c2.w); o23[7] = 0;
        ushort8v* dst = reinterpret_cast<ushort8v*>(wsImg + ((size_t)vb * HW_IMG + p4 * 4) * 4);
        dst[0] = o01;
        dst[1] = o23;
    } else if (blk < NB_IMG + NB_FEAT) {
        int idx = (blk - NB_IMG) * 256 + threadIdx.x;    // < 20*HW_HM
        int vb = idx / HW_HM;
        int pix = idx - vb * HW_HM;
        const float* src = feats + (size_t)vb * 32 * HW_HM + pix;
        ushort8v* dst = reinterpret_cast<ushort8v*>(wsFeat + (size_t)idx * 32);
#pragma unroll
        for (int k = 0; k < 4; ++k) {
            ushort8v o;
#pragma unroll
            for (int j = 0; j < 8; ++j)
                o[j] = bf16_rtne(src[(8 * k + j) * HW_HM]);
            dst[k] = o;
        }
    } else {
        int idx = (blk - NB_IMG - NB_FEAT) * 256 + threadIdx.x;
        if (idx < 16 * 3 * 64) {
            int l = idx & 63;
            int ks = (idx >> 6) % 3;
            int nt = idx / 192;
            int n = nt * 16 + (l & 15);
            int k0 = ks * 32 + (l >> 4) * 8;
            ushort8v o;
#pragma unroll
            for (int j = 0; j < 8; ++j) {
                int k = k0 + j;
                float v = (k < DIN) ? W1[k * HID + n] : 0.0f;
                o[j] = bf16_rtne(v);
            }
            reinterpret_cast<ushort8v*>(W1b)[idx] = o;
        } else if (idx < 16 * 3 * 64 + 16 * 8 * 64) {
            int id2 = idx - 16 * 3 * 64;
            int l = id2 & 63;
            int ks = (id2 >> 6) & 7;
            int nt = id2 >> 9;
            int n = nt * 16 + (l & 15);
            int k0 = ks * 32 + (l >> 4) * 8;
            ushort8v o;
#pragma unroll
            for (int j = 0; j < 8; ++j)
                o[j] = bf16_rtne(W2[(k0 + j) * HID + n]);
            reinterpret_cast<ushort8v*>(W2b)[id2] = o;
        }
    }
}

// ---------------- main fused kernel ----------------
__global__ __launch_bounds__(256, 6) void fused_denorm_project(
    const unsigned short* __restrict__ wsImg,  // [V*B, H, W, 4] bf16
    const unsigned short* __restrict__ wsFeat, // [V*B, h, w, 32] bf16
    const unsigned short* __restrict__ W1b,
    const unsigned short* __restrict__ W2b,
    const float* __restrict__ grids,  // [B,N,3]
    const float* __restrict__ Rm,     // [V,B,3,3]
    const float* __restrict__ Tm,     // [V,B,3,1]
    const float* __restrict__ fcam,   // [V,B,2]
    const float* __restrict__ ccam,   // [V,B,2]
    const float* __restrict__ kdist,  // [V,B,3]
    const float* __restrict__ pdist,  // [V,B,2]
    const float* __restrict__ trans,  // [2,3]
    const float* __restrict__ b1,     // [256]
    const float* __restrict__ b2,     // [256]
    const float* __restrict__ W3,     // [256,1]
    const float* __restrict__ b3,     // [1]
    float* __restrict__ out)          // [B*N]
{
    __shared__ unsigned short featb[BP * 96];    // 6 KB, swizzle ((p&7)<<4)
    __shared__ unsigned short h1T[BP * 256];     // 16 KB, same swizzle
    __shared__ float b1L[HID], b2L[HID], w3L[HID];
    __shared__ float partial[4][BP];

    const int tid = threadIdx.x;
    const int blk = blockIdx.x;
    const int b   = blk / (NPTS / BP);
    const int n0  = (blk % (NPTS / BP)) * BP;

    b1L[tid] = b1[tid];
    b2L[tid] = b2[tid];
    w3L[tid] = W3[tid];

    // ====== Phase A: one-view-per-lane projection + shared sampling ======
    {
        const int t = tid & 7;           // 8-lane group slot; feat chans 4t..4t+3
        const int p = tid >> 3;          // point within block (0..31)
        const int n = n0 + p;
        char* fbB = (char*)featb;
        const int rowoff = p * 192;
        const int sw = (p & 7) << 4;

        const float px = grids[(b * NPTS + n) * 3 + 0];
        const float py = grids[(b * NPTS + n) * 3 + 1];
        const float pz = grids[(b * NPTS + n) * 3 + 2];
        if (t == 1) {
            *(unsigned short*)(fbB + ((rowoff + 0) ^ sw)) = bf16_rtne(px * 1e-3f);
            *(unsigned short*)(fbB + ((rowoff + 2) ^ sw)) = bf16_rtne(py * 1e-3f);
            *(unsigned short*)(fbB + ((rowoff + 4) ^ sw)) = bf16_rtne(pz * 1e-3f);
        }
        {   // zero-pad k = 73..95
            int c0 = 73 + t * 3;
            int cnt = (t == 7) ? 2 : 3;
            for (int j = 0; j < cnt; ++j)
                *(unsigned short*)(fbB + ((rowoff + (c0 + j) * 2) ^ sw)) = 0;
        }

        // ---- owner lane (t < 5) computes view t's projection + taps ----
        Tap myF = {}; Tap myI = {};
        if (t < NVIEW) {
            const int vb = t * BATCH + b;
            const float* Rp = Rm + vb * 9;
            const float* Tp = Tm + vb * 3;
            float X = px - Tp[0], Y = py - Tp[1], Z = pz - Tp[2];
            float xc = Rp[0] * X + Rp[1] * Y + Rp[2] * Z;
            float yc = Rp[3] * X + Rp[4] * Y + Rp[5] * Z;
            float zc = Rp[6] * X + Rp[7] * Y + Rp[8] * Z;
            float inv = 1.0f / (zc + 1e-5f);
            float y0 = xc * inv, y1 = yc * inv;
            float r2 = y0 * y0 + y1 * y1;
            float k0 = kdist[vb * 3 + 0], k1 = kdist[vb * 3 + 1], k2 = kdist[vb * 3 + 2];
            float p0 = pdist[vb * 2 + 0], p1 = pdist[vb * 2 + 1];
            float radial = 1.0f + r2 * (k0 + r2 * (k1 + r2 * k2));
            float tn = p0 * y1 + p1 * y0;
            float scl = radial + 2.0f * tn;
            float uu = y0 * scl + p1 * r2;
            float vv = y1 * scl + p0 * r2;
            float xo = fcam[vb * 2 + 0] * uu + ccam[vb * 2 + 0];
            float yo = fcam[vb * 2 + 1] * vv + ccam[vb * 2 + 1];
            xo = fminf(fmaxf(xo, -1.0f), 1920.0f);
            yo = fminf(fmaxf(yo, -1.0f), 1920.0f);
            float xr = trans[0] * xo + trans[1] * yo + trans[2];
            float yr = trans[3] * xo + trans[4] * yo + trans[5];
            float gx = xr * (1.0f / (float)(IMG_W - 1)) * 2.0f - 1.0f;
            float gy = yr * (1.0f / (float)(IMG_H - 1)) * 2.0f - 1.0f;
            make_tap(gx, gy, HM_W, HM_H, myF);
            make_tap(gx, gy, IMG_W, IMG_H, myI);
        }

        // ---- feat sampling: all 8 lanes, taps broadcast from owner lane ----
        float4 s4 = f4zero(), q4 = f4zero();
        const int lb = (tid & 63) & 56;     // wave-local group base
        for (int v = 0; v < NVIEW; ++v) {
            const int src = lb + v;
            Tap tF;
            tF.o00 = __shfl(myF.o00, src, 64);
            tF.o01 = __shfl(myF.o01, src, 64);
            tF.o10 = __shfl(myF.o10, src, 64);
            tF.o11 = __shfl(myF.o11, src, 64);
            tF.w00 = __shfl(myF.w00, src, 64);
            tF.w01 = __shfl(myF.w01, src, 64);
            tF.w10 = __shfl(myF.w10, src, 64);
            tF.w11 = __shfl(myF.w11, src, 64);
            const unsigned short* fb = wsFeat + (size_t)(v * BATCH + b) * HW_HM * 32 + t * 4;
            ushort4v a00 = *reinterpret_cast<const ushort4v*>(fb + (size_t)tF.o00 * 32);
            ushort4v a01 = *reinterpret_cast<const ushort4v*>(fb + (size_t)tF.o01 * 32);
            ushort4v a10 = *reinterpret_cast<const ushort4v*>(fb + (size_t)tF.o10 * 32);
            ushort4v a11 = *reinterpret_cast<const ushort4v*>(fb + (size_t)tF.o11 * 32);
            float4 val = f4zero();
            val = tapacc(a00, tF.w00, val);
            val = tapacc(a01, tF.w01, val);
            val = tapacc(a10, tF.w10, val);
            val = tapacc(a11, tF.w11, val);
            s4 = f4add(s4, val);
            q4 = f4addsq(q4, val);
        }

        // ---- img sampling: owner lane samples its own view ----
        float4 si = f4zero(), qi = f4zero();
        if (t < NVIEW) {
            const unsigned short* ib = wsImg + (size_t)(t * BATCH + b) * HW_IMG * 4;
            ushort4v i00 = *reinterpret_cast<const ushort4v*>(ib + (size_t)myI.o00 * 4);
            ushort4v i01 = *reinterpret_cast<const ushort4v*>(ib + (size_t)myI.o01 * 4);
            ushort4v i10 = *reinterpret_cast<const ushort4v*>(ib + (size_t)myI.o10 * 4);
            ushort4v i11 = *reinterpret_cast<const ushort4v*>(ib + (size_t)myI.o11 * 4);
            float4 vi = f4zero();
            vi = tapacc(i00, myI.w00, vi);
            vi = tapacc(i01, myI.w01, vi);
            vi = tapacc(i10, myI.w10, vi);
            vi = tapacc(i11, myI.w11, vi);
            si = vi;
            qi = f4addsq(f4zero(), vi);
        }
        // 8-lane butterfly reduce of si/qi (lanes 5..7 contribute zero)
#pragma unroll
        for (int off = 1; off <= 4; off <<= 1) {
            si.x += __shfl_xor(si.x, off, 64);
            si.y += __shfl_xor(si.y, off, 64);
            si.z += __shfl_xor(si.z, off, 64);
            qi.x += __shfl_xor(qi.x, off, 64);
            qi.y += __shfl_xor(qi.y, off, 64);
            qi.z += __shfl_xor(qi.z, off, 64);
        }

        const float inv5 = 1.0f / (float)NVIEW;
        {
            float m0 = s4.x * inv5, m1 = s4.y * inv5, m2 = s4.z * inv5, m3 = s4.w * inv5;
            int cm = 6 + 4 * t;
            int cv = 41 + 4 * t;
            *(unsigned short*)(fbB + ((rowoff + (cm + 0) * 2) ^ sw)) = bf16_rtne(m0);
            *(unsigned short*)(fbB + ((rowoff + (cm + 1) * 2) ^ sw)) = bf16_rtne(m1);
            *(unsigned short*)(fbB + ((rowoff + (cm + 2) * 2) ^ sw)) = bf16_rtne(m2);
            *(unsigned short*)(fbB + ((rowoff + (cm + 3) * 2) ^ sw)) = bf16_rtne(m3);
            *(unsigned short*)(fbB + ((rowoff + (cv + 0) * 2) ^ sw)) = bf16_rtne(expf(-(q4.x * inv5 - m0 * m0)));
            *(unsigned short*)(fbB + ((rowoff + (cv + 1) * 2) ^ sw)) = bf16_rtne(expf(-(q4.y * inv5 - m1 * m1)));
            *(unsigned short*)(fbB + ((rowoff + (cv + 2) * 2) ^ sw)) = bf16_rtne(expf(-(q4.z * inv5 - m2 * m2)));
            *(unsigned short*)(fbB + ((rowoff + (cv + 3) * 2) ^ sw)) = bf16_rtne(expf(-(q4.w * inv5 - m3 * m3)));
        }
        if (t == 0) {
            float m0 = si.x * inv5, m1 = si.y * inv5, m2 = si.z * inv5;
            *(unsigned short*)(fbB + ((rowoff + 3 * 2) ^ sw)) = bf16_rtne(m0);
            *(unsigned short*)(fbB + ((rowoff + 4 * 2) ^ sw)) = bf16_rtne(m1);
            *(unsigned short*)(fbB + ((rowoff + 5 * 2) ^ sw)) = bf16_rtne(m2);
            *(unsigned short*)(fbB + ((rowoff + 38 * 2) ^ sw)) = bf16_rtne(expf(-(qi.x * inv5 - m0 * m0)));
            *(unsigned short*)(fbB + ((rowoff + 39 * 2) ^ sw)) = bf16_rtne(expf(-(qi.y * inv5 - m1 * m1)));
            *(unsigned short*)(fbB + ((rowoff + 40 * 2) ^ sw)) = bf16_rtne(expf(-(qi.z * inv5 - m2 * m2)));
        }
    }
    __syncthreads();

    // ================= MLP via MFMA (transposed: h^T[n][p]) =================
    const int l   = tid & 63;
    const int w   = tid >> 6;          // wave 0..3, owns n-tiles w*4..w*4+3
    const int g   = l >> 4;            // lane group
    const int c16 = l & 15;            // point-within-tile

    // ---- layer 1 ----
    {
        f32x4 acc[4][2];
#pragma unroll
        for (int nl = 0; nl < 4; ++nl)
#pragma unroll
            for (int pt = 0; pt < 2; ++pt) acc[nl][pt] = (f32x4)0.0f;

        const bf16x8* wfrag = reinterpret_cast<const bf16x8*>(W1b);
#pragma unroll
        for (int ks = 0; ks < 3; ++ks) {
            bf16x8 bfr[2];
#pragma unroll
            for (int pt = 0; pt < 2; ++pt) {
                int p = pt * 16 + c16;
                int off = (p * 192 + (ks * 32 + g * 8) * 2) ^ ((p & 7) << 4);
                bfr[pt] = *reinterpret_cast<const bf16x8*>((const char*)featb + off);
            }
#pragma unroll
            for (int nl = 0; nl < 4; ++nl) {
                int nt = w * 4 + nl;
                bf16x8 a = wfrag[(nt * 3 + ks) * 64 + l];
                acc[nl][0] = __builtin_amdgcn_mfma_f32_16x16x32_bf16(a, bfr[0], acc[nl][0], 0, 0, 0);
                acc[nl][1] = __builtin_amdgcn_mfma_f32_16x16x32_bf16(a, bfr[1], acc[nl][1], 0, 0, 0);
            }
        }
#pragma unroll
        for (int nl = 0; nl < 4; ++nl) {
            int nb = (w * 4 + nl) * 16 + g * 4;
            float bb0 = b1L[nb + 0], bb1 = b1L[nb + 1], bb2 = b1L[nb + 2], bb3v = b1L[nb + 3];
#pragma unroll
            for (int pt = 0; pt < 2; ++pt) {
                int p = pt * 16 + c16;
                ushort4v pk;
                pk[0] = bf16_rtne(fmaxf(acc[nl][pt][0] + bb0, 0.0f));
                pk[1] = bf16_rtne(fmaxf(acc[nl][pt][1] + bb1, 0.0f));
                pk[2] = bf16_rtne(fmaxf(acc[nl][pt][2] + bb2, 0.0f));
                pk[3] = bf16_rtne(fmaxf(acc[nl][pt][3] + bb3v, 0.0f));
                int off = (p * 512 + nb * 2) ^ ((p & 7) << 4);
                *reinterpret_cast<ushort4v*>((char*)h1T + off) = pk;
            }
        }
    }
    __syncthreads();

    // ---- layer 2 + layer 3 ----
    {
        f32x4 acc[4][2];
#pragma unroll
        for (int nl = 0; nl < 4; ++nl)
#pragma unroll
            for (int pt = 0; pt < 2; ++pt) acc[nl][pt] = (f32x4)0.0f;

        const bf16x8* wfrag = reinterpret_cast<const bf16x8*>(W2b);
#pragma unroll
        for (int ks = 0; ks < 8; ++ks) {
            bf16x8 bfr[2];
#pragma unroll
            for (int pt = 0; pt < 2; ++pt) {
                int p = pt * 16 + c16;
                int off = (p * 512 + (ks * 32 + g * 8) * 2) ^ ((p & 7) << 4);
                bfr[pt] = *reinterpret_cast<const bf16x8*>((const char*)h1T + off);
            }
#pragma unroll
            for (int nl = 0; nl < 4; ++nl) {
                int nt = w * 4 + nl;
                bf16x8 a = wfrag[(nt * 8 + ks) * 64 + l];
                acc[nl][0] = __builtin_amdgcn_mfma_f32_16x16x32_bf16(a, bfr[0], acc[nl][0], 0, 0, 0);
                acc[nl][1] = __builtin_amdgcn_mfma_f32_16x16x32_bf16(a, bfr[1], acc[nl][1], 0, 0, 0);
            }
        }
        float s0 = 0.0f, s1 = 0.0f;
#pragma unroll
        for (int nl = 0; nl < 4; ++nl) {
            int nb = (w * 4 + nl) * 16 + g * 4;
#pragma unroll
            for (int r = 0; r < 4; ++r) {
                float b2v = b2L[nb + r];
                float w3v = w3L[nb + r];
                s0 += fmaxf(acc[nl][0][r] + b2v, 0.0f) * w3v;
                s1 += fmaxf(acc[nl][1][r] + b2v, 0.0f) * w3v;
            }
        }
        s0 += __shfl_xor(s0, 16, 64);
        s0 += __shfl_xor(s0, 32, 64);
        s1 += __shfl_xor(s1, 16, 64);
        s1 += __shfl_xor(s1, 32, 64);
        if (g == 0) {
            partial[w][c16]      = s0;
            partial[w][16 + c16] = s1;
        }
    }
    __syncthreads();

    if (tid < BP) {
        float v = partial[0][tid] + partial[1][tid] + partial[2][tid] + partial[3][tid] + b3[0];
        out[b * NPTS + n0 + tid] = 1.0f / (1.0f + expf(-v));   // 1-exp(-softplus) == sigmoid
    }
}

extern "C" void kernel_launch(void* const* d_in, const int* in_sizes, int n_in,
                              void* d_out, int out_size, void* d_ws, size_t ws_size,
                              hipStream_t stream) {
    const float* imgs  = (const float*)d_in[0];
    const float* feats = (const float*)d_in[1];
    const float* grids = (const float*)d_in[2];
    const float* Rm    = (const float*)d_in[3];
    const float* Tm    = (const float*)d_in[4];
    const float* fcam  = (const float*)d_in[5];
    const float* ccam  = (const float*)d_in[6];
    const float* kdist = (const float*)d_in[7];
    const float* pdist = (const float*)d_in[8];
    const float* trans = (const float*)d_in[9];
    const float* W1    = (const float*)d_in[10];
    const float* b1    = (const float*)d_in[11];
    const float* W2    = (const float*)d_in[12];
    const float* b2    = (const float*)d_in[13];
    const float* W3    = (const float*)d_in[14];
    const float* b3    = (const float*)d_in[15];
    float* out = (float*)d_out;

    unsigned short* wsImg  = (unsigned short*)d_ws;                       // 78.6 MB
    unsigned short* wsFeat = wsImg + (size_t)NVIEW * BATCH * HW_IMG * 4;  // 39.3 MB
    unsigned short* W1b    = wsFeat + (size_t)NVIEW * BATCH * HW_HM * 32;
    unsigned short* W2b    = W1b + 16 * 3 * 64 * 8;

    prep_all<<<NB_IMG + NB_FEAT + NB_W, 256, 0, stream>>>(
        imgs, feats, W1, W2, wsImg, wsFeat, W1b, W2b);

    const int nblocks = BATCH * (NPTS / BP);  // 16000
    fused_denorm_project<<<nblocks, 256, 0, stream>>>(
        wsImg, wsFeat, W1b, W2b, grids, Rm, Tm, fcam, ccam, kdist, pdist, trans,
        b1, b2, W3, b3, out);
}